// Round 5
// baseline (1064.930 us; speedup 1.0000x reference)
//
#include <hip/hip_runtime.h>
#include <hip/hip_bf16.h>
#include <cstdint>

// ---------------------------------------------------------------------------
// SANA MS-AdaLN block on MI355X.
// R1: LN stats via per-block partials. R3: 128x256 regressed (occupancy).
// R4: SQ_LDS_BANK_CONFLICT = 8/gload_lds instr is structural DMA-fill cost.
// R5a/R6: GROUP_M + XCD-chunked bijective swizzle (FETCH 401->95 MB).
// R7: 2-phase dbuf + counted vmcnt(4): VALUBusy 39->16, MfmaUtil 23->26.
// R8: 3-buf 2-deep prefetch vmcnt(8): NEUTRAL -> not load-latency-bound.
//   128²/BK=32 structure is LDS-throughput/structure-bound (m97-class
//   ceiling). Path past it: 256² phase-interleaved template.
// R9: gemm256 - 256x256, BK=64, 8 waves (2Mx4N), 128KB LDS dbuf, 4-phase
//   K-tile, one counted vmcnt(8)/tile, XOR swizzle on gload SOURCE + ds_read.
//   Bench: container failed twice (no counters; infra degraded that round).
// R10: R9 re-audited (no OOB / barrier-divergence / vmcnt bugs found) and
//   HARDENED per rule #18 + m201 template discipline: sched_barrier(0) after
//   every counted s_waitcnt, and asm memory fences at every phase boundary so
//   STAGE/ds_read cannot be compiler-moved across a raw s_barrier (the one
//   hazard class R9 left open vs the verified template).
// ---------------------------------------------------------------------------

typedef __bf16 bf16;
typedef bf16 bf16x8 __attribute__((ext_vector_type(8)));
typedef bf16 bf16x4 __attribute__((ext_vector_type(4)));
typedef float f32x4 __attribute__((ext_vector_type(4)));

typedef const __attribute__((address_space(1))) void gas_void;
typedef __attribute__((address_space(3))) void las_void;

__device__ __forceinline__ void gload16(const bf16* g, bf16* l) {
    __builtin_amdgcn_global_load_lds((gas_void*)g, (las_void*)l, 16, 0, 0);
}

// ---- problem constants ----
#define BB 4
#define CC 288
#define HW 4096          // 64*64
#define C6 1728
#define DD 1152
#define SEQ 1026
#define RTOT 4104        // 4*1026
#define NTOK 1024
#define HF 4608
#define HF2 9216
#define NPB 1179648      // elements per batch sample (288*4096)

// ---- workspace layout (bytes) ----
static constexpr size_t OFF_SUMS = 0;                                   // 16 floats
static constexpr size_t OFF_SS   = 256;                                 // bf16 [1728][16384]
static constexpr size_t SS_BYTES = (size_t)C6 * 16384 * 2;              // 56,623,104
static constexpr size_t OFF_R2   = OFF_SS + SS_BYTES;
// phase A
static constexpr size_t OFF_PART1= OFF_R2;                              // f32 [1152][2]
static constexpr size_t OFF_A1   = OFF_R2;                              // bf16 [16384][1728]
// phase B
static constexpr size_t OFF_T    = OFF_R2;                              // bf16 [4104][1152]
static constexpr size_t OFF_QKV  = OFF_T   + (size_t)RTOT*DD*2;         // bf16 [3456][4104]
static constexpr size_t OFF_PART2= OFF_QKV;                             // f32 [18432][2]
static constexpr size_t OFF_VK   = OFF_QKV + (size_t)3456*RTOT*2;       // f32  [144][1056]
static constexpr size_t OFF_ATT  = OFF_VK  + (size_t)144*1056*4;        // bf16 [4104][1152]
static constexpr size_t OFF_APROJ= OFF_ATT + (size_t)RTOT*DD*2;         // bf16 [1152][4104]
// phase C
static constexpr size_t OFF_T2   = OFF_R2;                              // bf16 [4096][1152]
static constexpr size_t OFF_Y    = OFF_T2  + (size_t)4096*DD*2;         // bf16 [4096][9216]
static constexpr size_t OFF_G    = OFF_Y   + (size_t)4096*HF2*2;        // bf16 [4096][4608]
static constexpr size_t OFF_M    = OFF_G   + (size_t)4096*HF*2;         // bf16 [1152][4096]
// converted weights (persistent)
static constexpr size_t OFF_W    = OFF_R2  + 132120576;
static constexpr size_t OFF_WSS  = OFF_W;
static constexpr size_t OFF_WQKV = OFF_WSS  + (size_t)C6*C6*2;
static constexpr size_t OFF_WPROJ= OFF_WQKV + (size_t)3456*DD*2;
static constexpr size_t OFF_WINV = OFF_WPROJ+ (size_t)DD*DD*2;
static constexpr size_t OFF_WPW  = OFF_WINV + (size_t)HF2*DD*2;

// ---------------------------------------------------------------------------
// fp32 -> bf16 weight conversion
__global__ __launch_bounds__(256) void cvt_bf16(const float* __restrict__ s,
                                                bf16* __restrict__ d, int n4) {
    int i = blockIdx.x * 256 + threadIdx.x;
    if (i < n4) {
        float4 v = ((const float4*)s)[i];
        bf16x4 o = {(bf16)v.x, (bf16)v.y, (bf16)v.z, (bf16)v.w};
        ((bf16x4*)d)[i] = o;
    }
}

// ---------------------------------------------------------------------------
__device__ __forceinline__ void block_reduce2_store(float s1, float s2, float* dst) {
    #pragma unroll
    for (int o = 32; o > 0; o >>= 1) { s1 += __shfl_down(s1, o); s2 += __shfl_down(s2, o); }
    __shared__ float r1[4], r2[4];
    int wave = threadIdx.x >> 6, lane = threadIdx.x & 63;
    if (lane == 0) { r1[wave] = s1; r2[wave] = s2; }
    __syncthreads();
    if (threadIdx.x == 0) {
        dst[0] = r1[0] + r1[1] + r1[2] + r1[3];
        dst[1] = r2[0] + r2[1] + r2[2] + r2[3];
    }
}

__global__ __launch_bounds__(256) void ln_stats(const float* __restrict__ x, float* __restrict__ part) {
    const float* base = x + (size_t)blockIdx.x * 4096;
    float s1 = 0.f, s2 = 0.f;
    #pragma unroll
    for (int it = 0; it < 4; it++) {
        float4 v = ((const float4*)base)[it * 256 + threadIdx.x];
        s1 += v.x + v.y + v.z + v.w;
        s2 += v.x * v.x + v.y * v.y + v.z * v.z + v.w * v.w;
    }
    block_reduce2_store(s1, s2, part + (size_t)blockIdx.x * 2);
}

__global__ __launch_bounds__(256) void reduce_part(const float* __restrict__ part, float* __restrict__ sums,
                                                   int nper, int out_off) {
    int b = blockIdx.x;
    float s1 = 0.f, s2 = 0.f;
    for (int i = threadIdx.x; i < nper; i += 256) {
        s1 += part[(size_t)(b * nper + i) * 2];
        s2 += part[(size_t)(b * nper + i) * 2 + 1];
    }
    block_reduce2_store(s1, s2, sums + out_off + b * 2);
}

// ---------------------------------------------------------------------------
// silu(cond) transpose: (b, k, hw) f32 -> A1[(b,hw)][k] bf16. grid (64,27,4)
__global__ __launch_bounds__(256) void prep_cond(const float* __restrict__ cond, bf16* __restrict__ A1) {
    __shared__ float tile[64][65];
    int b = blockIdx.z, k0 = blockIdx.y * 64, h0 = blockIdx.x * 64;
    int col = threadIdx.x & 63, r4 = threadIdx.x >> 6;
    const float* src = cond + ((size_t)b * C6 + k0) * HW + h0;
    #pragma unroll
    for (int p = 0; p < 16; p++) {
        int kk = r4 + p * 4;
        float v = src[(size_t)kk * HW + col];
        tile[col][kk] = v / (1.f + __expf(-v));
    }
    __syncthreads();
    bf16* dst = A1 + ((size_t)(b * HW + h0)) * C6 + k0;
    #pragma unroll
    for (int p = 0; p < 16; p++) {
        int rr = r4 + p * 4;
        dst[(size_t)rr * C6 + col] = (bf16)tile[rr][col];
    }
}

// ---------------------------------------------------------------------------
// gemm256: 256x256 tile, BK=64, 512 threads (8 waves, 2Mx4N), dbuf LDS,
// 4-phase interleave with counted vmcnt(8). C[m][n]=sum_k A[m][k]B[n][k].
template <int EP, int BIAS>
__global__ __launch_bounds__(512, 2) void gemm256(const bf16* __restrict__ A, const bf16* __restrict__ B,
                                                  const float* __restrict__ bias, bf16* __restrict__ C,
                                                  int M, int N, int K, int reluLimit) {
    __shared__ __align__(16) bf16 As[2][256 * 64];
    __shared__ __align__(16) bf16 Bs[2][256 * 64];
    const int tid = threadIdx.x, wave = tid >> 6, lane = tid & 63;

    // ---- XCD-chunked GROUP_M grid swizzle (bijection over the grid) ----
    const int nx = gridDim.x, ny = gridDim.y, G = 8;
    int idx = blockIdx.y * nx + blockIdx.x;
    int total = nx * ny;
    int q = total >> 3, rm = total & 7;
    int xcd = idx & 7, slot = idx >> 3;
    int vid = (xcd < rm ? xcd * (q + 1) : rm * (q + 1) + (xcd - rm) * q) + slot;
    int band = vid / (G * nx);
    int r = vid - band * (G * nx);
    int gm = min(G, ny - band * G);
    const int m0 = (band * G + r % gm) * 256;
    const int n0 = (r / gm) * 256;

    // ---- staging: per-wave gload_lds writes 1KB linear (base + lane*16).
    // lane covers row = wave*8 + (lane>>3) (+64*rr +128*half), kchunk=(lane&7).
    // Source pre-swizzled: kchunk ^= (row&7) (involution; read applies same).
    const int srow_l = (wave << 3) + (lane >> 3);            // 0..63
    const int sk_el  = (((lane & 7) ^ (lane >> 3)) << 3);    // swizzled k element
    const bf16* pA[4]; const bf16* pB[4];
    #pragma unroll
    for (int g = 0; g < 4; ++g) {
        pA[g] = A + (size_t)min(m0 + g * 64 + srow_l, M - 1) * K + sk_el;
        pB[g] = B + (size_t)min(n0 + g * 64 + srow_l, N - 1) * K + sk_el;
    }
    auto STAGE_A = [&](int buf, int half) {
        #pragma unroll
        for (int rr = 0; rr < 2; ++rr) {
            gload16(pA[half * 2 + rr], &As[buf][half * 8192 + rr * 4096 + (wave << 9)]);
            pA[half * 2 + rr] += 64;
        }
    };
    auto STAGE_B = [&](int buf, int half) {
        #pragma unroll
        for (int rr = 0; rr < 2; ++rr) {
            gload16(pB[half * 2 + rr], &Bs[buf][half * 8192 + rr * 4096 + (wave << 9)]);
            pB[half * 2 + rr] += 64;
        }
    };

    // ---- fragment reads (swizzled to match staged layout) ----
    const int wm_w = (wave >> 2) * 128, wn_w = (wave & 3) * 64;
    const int l15 = lane & 15;
    const int fswz = (l15 & 7) << 4;          // (row&7)*16 bytes
    const int rk16 = (lane >> 4) << 4;        // 0,16,32,48 (k chunk bytes)

    bf16x8 af[8], bv[8];
    f32x4 acc[8][4];
    #pragma unroll
    for (int i = 0; i < 8; i++)
        #pragma unroll
        for (int j = 0; j < 4; j++) acc[i][j] = (f32x4){0.f, 0.f, 0.f, 0.f};

    auto LDA = [&](const bf16* base, int qm) {
        #pragma unroll
        for (int il = 0; il < 4; ++il)
            #pragma unroll
            for (int ks = 0; ks < 2; ++ks) {
                int row = wm_w + (qm * 4 + il) * 16 + l15;
                int kb  = (ks * 64 + rk16) ^ fswz;
                af[il * 2 + ks] = *(const bf16x8*)(base + row * 64 + (kb >> 1));
            }
    };
    auto LDB = [&](const bf16* base) {
        #pragma unroll
        for (int j = 0; j < 4; ++j)
            #pragma unroll
            for (int ks = 0; ks < 2; ++ks) {
                int row = wn_w + j * 16 + l15;
                int kb  = (ks * 64 + rk16) ^ fswz;
                bv[j * 2 + ks] = *(const bf16x8*)(base + row * 64 + (kb >> 1));
            }
    };
    auto MF = [&](int qm, int jh) {
        __builtin_amdgcn_s_setprio(1);
        #pragma unroll
        for (int il = 0; il < 4; ++il)
            #pragma unroll
            for (int jl = 0; jl < 2; ++jl)
                #pragma unroll
                for (int ks = 0; ks < 2; ++ks)
                    acc[qm * 4 + il][jh * 2 + jl] = __builtin_amdgcn_mfma_f32_16x16x32_bf16(
                        af[il * 2 + ks], bv[(jh * 2 + jl) * 2 + ks], acc[qm * 4 + il][jh * 2 + jl], 0, 0, 0);
        __builtin_amdgcn_s_setprio(0);
    };

    // one K-tile = 4 phases. Regions of buf[cur] freed by phase barriers host
    // tile t+2's halves: p1<-B.h0, p2<-B.h1, p3<-A.h0+A.h1. vmcnt(8) at p3
    // retires tile t+1's 8 loads; t+2's 8 stay in flight across the barrier.
    // Every phase boundary carries an asm memory fence so STAGE/ds_read can't
    // be compiler-moved across a raw s_barrier (R10 hardening).
    auto TILE = [&](int t, bool stage_next, bool last_vm) {
        const int cur = t & 1;
        const bf16* Ab = &As[cur][0];
        const bf16* Bb = &Bs[cur][0];
        // p0: ds A-quarter0 + B-all ; MFMA q(0, jh0)
        LDA(Ab, 0);
        LDB(Bb);
        asm volatile("s_waitcnt lgkmcnt(0)" ::: "memory");
        __builtin_amdgcn_sched_barrier(0);
        __builtin_amdgcn_s_barrier();
        MF(0, 0);
        asm volatile("" ::: "memory");
        __builtin_amdgcn_s_barrier();
        asm volatile("" ::: "memory");
        // p1: stage B.h0(t+2) ; MFMA q(0, jh1)
        if (stage_next) STAGE_B(cur, 0);
        asm volatile("" ::: "memory");
        __builtin_amdgcn_s_barrier();
        MF(0, 1);
        asm volatile("" ::: "memory");
        __builtin_amdgcn_s_barrier();
        asm volatile("" ::: "memory");
        // p2: ds A-quarter1 ; stage B.h1(t+2) ; MFMA q(1, jh0)
        LDA(Ab, 1);
        if (stage_next) STAGE_B(cur, 1);
        asm volatile("s_waitcnt lgkmcnt(0)" ::: "memory");
        __builtin_amdgcn_sched_barrier(0);
        __builtin_amdgcn_s_barrier();
        MF(1, 0);
        asm volatile("" ::: "memory");
        __builtin_amdgcn_s_barrier();
        asm volatile("" ::: "memory");
        // p3: stage A.h0+h1(t+2) ; counted vmcnt ; MFMA q(1, jh1)
        if (stage_next) {
            STAGE_A(cur, 0); STAGE_A(cur, 1);
            asm volatile("s_waitcnt vmcnt(8)" ::: "memory");
            __builtin_amdgcn_sched_barrier(0);
        } else if (last_vm) {
            asm volatile("s_waitcnt vmcnt(0)" ::: "memory");
            __builtin_amdgcn_sched_barrier(0);
        }
        __builtin_amdgcn_s_barrier();
        MF(1, 1);
        asm volatile("" ::: "memory");
        __builtin_amdgcn_s_barrier();
        asm volatile("" ::: "memory");
    };

    const int nt = K >> 6;                     // 27 / 18 (all >= 3)
    // prologue: stage tiles 0,1 (order per tile: B0,B1,A0,A1 matches steady)
    #pragma unroll
    for (int tt = 0; tt < 2; ++tt) {
        STAGE_B(tt, 0); STAGE_B(tt, 1);
        STAGE_A(tt, 0); STAGE_A(tt, 1);
    }
    asm volatile("s_waitcnt vmcnt(8)" ::: "memory");   // tile0 landed
    __builtin_amdgcn_sched_barrier(0);
    __builtin_amdgcn_s_barrier();
    asm volatile("" ::: "memory");
    for (int t = 0; t < nt - 2; ++t) TILE(t, true, false);
    TILE(nt - 2, false, true);
    TILE(nt - 1, false, false);

    // epilogue
    const int mq = (lane >> 4) * 4, nl = lane & 15;
    #pragma unroll
    for (int i = 0; i < 8; i++) {
        #pragma unroll
        for (int j = 0; j < 4; j++) {
            int n = n0 + wn_w + j * 16 + nl;
            if (n < N) {
                #pragma unroll
                for (int r2 = 0; r2 < 4; r2++) {
                    int m = m0 + wm_w + i * 16 + mq + r2;
                    if (m < M) {
                        float v = acc[i][j][r2];
                        if (BIAS == 1) v += bias[m];
                        else if (BIAS == 2) v += bias[n];
                        if (EP == 1) { if (m < reluLimit) v = fmaxf(v, 0.f); }
                        else if (EP == 2) { v = v / (1.f + __expf(-v)); }
                        C[(size_t)m * N + n] = (bf16)v;
                    }
                }
            }
        }
    }
}

// ---------------------------------------------------------------------------
// gemm_bt (128x128, R8 structure): kept for small-grid GEMMs (proj/project).
template <int EP, int BIAS>
__global__ __launch_bounds__(256) void gemm_bt(const bf16* __restrict__ A, const bf16* __restrict__ B,
                                               const float* __restrict__ bias, bf16* __restrict__ C,
                                               int M, int N, int K, int reluLimit) {
    __shared__ __align__(16) bf16 As[3][128 * 32];
    __shared__ __align__(16) bf16 Bs[3][128 * 32];
    const int tid = threadIdx.x, wave = tid >> 6, lane = tid & 63;

    const int nx = gridDim.x, ny = gridDim.y, G = 8;
    int idx = blockIdx.y * nx + blockIdx.x;
    int total = nx * ny;
    int q = total >> 3, rm = total & 7;
    int xcd = idx & 7, slot = idx >> 3;
    int vid = (xcd < rm ? xcd * (q + 1) : rm * (q + 1) + (xcd - rm) * q) + slot;
    int band = vid / (G * nx);
    int r = vid - band * (G * nx);
    int gm = min(G, ny - band * G);
    const int m0 = (band * G + r % gm) * 128;
    const int n0 = (r / gm) * 128;

    const int c0 = wave * 128 + lane;
    const int c1 = c0 + 64;
    const int sw = ((c0 >> 2) & 3) ^ ((c0 >> 4) & 3);
    const int ka = (((c0 & 3) ^ sw)) * 8;
    int ra0 = min(m0 + (c0 >> 2), M - 1), ra1 = min(m0 + (c1 >> 2), M - 1);
    int rb0 = min(n0 + (c0 >> 2), N - 1), rb1 = min(n0 + (c1 >> 2), N - 1);
    const bf16* gA0 = A + (size_t)ra0 * K + ka;
    const bf16* gA1 = A + (size_t)ra1 * K + ka;
    const bf16* gB0 = B + (size_t)rb0 * K + ka;
    const bf16* gB1 = B + (size_t)rb1 * K + ka;

    const int wm = (wave >> 1) * 64, wn = (wave & 1) * 64;
    const int l15 = lane & 15;
    const int sr = (l15 & 3) ^ ((l15 >> 2) & 3);
    const int fc = ((lane >> 4) ^ sr) * 8;
    const int fao = (wm + l15) * 32 + fc;
    const int fbo = (wn + l15) * 32 + fc;
    const int lwo = wave * 1024;

    f32x4 acc[4][4];
    #pragma unroll
    for (int i = 0; i < 4; i++)
        #pragma unroll
        for (int j = 0; j < 4; j++) acc[i][j] = (f32x4){0.f, 0.f, 0.f, 0.f};

    auto STAGE = [&](int buf) {
        gload16(gA0, &As[buf][lwo]);
        gload16(gA1, &As[buf][lwo + 512]);
        gload16(gB0, &Bs[buf][lwo]);
        gload16(gB1, &Bs[buf][lwo + 512]);
        gA0 += 32; gA1 += 32; gB0 += 32; gB1 += 32;
    };
    auto COMP = [&](int buf) {
        const bf16* fa = &As[buf][fao];
        const bf16* fb = &Bs[buf][fbo];
        bf16x8 af[4], bvv[4];
        #pragma unroll
        for (int i = 0; i < 4; i++) af[i] = *(const bf16x8*)(fa + i * 16 * 32);
        #pragma unroll
        for (int j = 0; j < 4; j++) bvv[j] = *(const bf16x8*)(fb + j * 16 * 32);
        #pragma unroll
        for (int i = 0; i < 4; i++)
            #pragma unroll
            for (int j = 0; j < 4; j++)
                acc[i][j] = __builtin_amdgcn_mfma_f32_16x16x32_bf16(af[i], bvv[j], acc[i][j], 0, 0, 0);
    };
    auto STEP = [&](int cbuf, int sbuf) {
        STAGE(sbuf);
        asm volatile("s_waitcnt vmcnt(8)" ::: "memory");
        __builtin_amdgcn_s_barrier();
        asm volatile("" ::: "memory");
        COMP(cbuf);
        asm volatile("" ::: "memory");
        __builtin_amdgcn_s_barrier();
    };

    const int nt = K >> 5;
    STAGE(0);
    STAGE(1);
    for (int it = 0; it < nt / 3 - 1; ++it) {
        STEP(0, 2);
        STEP(1, 0);
        STEP(2, 1);
    }
    STEP(0, 2);
    asm volatile("s_waitcnt vmcnt(4)" ::: "memory");
    __builtin_amdgcn_s_barrier();
    asm volatile("" ::: "memory");
    COMP(1);
    asm volatile("" ::: "memory");
    asm volatile("s_waitcnt vmcnt(0)" ::: "memory");
    __builtin_amdgcn_s_barrier();
    asm volatile("" ::: "memory");
    COMP(2);

    const int mq = (lane >> 4) * 4, nl = lane & 15;
    #pragma unroll
    for (int i = 0; i < 4; i++) {
        #pragma unroll
        for (int j = 0; j < 4; j++) {
            int n = n0 + wn + j * 16 + nl;
            if (n < N) {
                #pragma unroll
                for (int r2 = 0; r2 < 4; r2++) {
                    int m = m0 + wm + i * 16 + mq + r2;
                    if (m < M) {
                        float v = acc[i][j][r2];
                        if (BIAS == 1) v += bias[m];
                        else if (BIAS == 2) v += bias[n];
                        if (EP == 1) { if (m < reluLimit) v = fmaxf(v, 0.f); }
                        else if (EP == 2) { v = v / (1.f + __expf(-v)); }
                        C[(size_t)m * N + n] = (bf16)v;
                    }
                }
            }
        }
    }
}

// ---------------------------------------------------------------------------
// token build (coalesced): grid (9 cchunk, 32 n1, 4 b), block 256.
__global__ __launch_bounds__(256) void build_tok_t(const float* __restrict__ xs, const bf16* __restrict__ ss,
                                                   const float* __restrict__ sums, int soff, int shb, int scb,
                                                   bf16* __restrict__ dst, int tokoff, int seqstride) {
    __shared__ bf16 tl[32][132];
    int cch = blockIdx.x, n1 = blockIdx.y, b = blockIdx.z;
    int c0 = cch * 32;
    int tid = threadIdx.x, cl = tid >> 3, wseg = tid & 7;

    float mu = sums[soff + b * 2] * (1.f / (float)NPB);
    float var = sums[soff + b * 2 + 1] * (1.f / (float)NPB) - mu * mu;
    float rsig = rsqrtf(var + 1e-6f);

    int c = c0 + cl;
    #pragma unroll
    for (int hh = 0; hh < 2; hh++) {
        int hw = (2 * n1 + hh) * 64 + wseg * 8;
        const float* xp = xs + ((size_t)b * CC + c) * HW + hw;
        float4 x0 = ((const float4*)xp)[0];
        float4 x1 = ((const float4*)xp)[1];
        bf16x8 scv = *(const bf16x8*)(ss + (size_t)(scb + c) * 16384 + b * HW + hw);
        bf16x8 shv = *(const bf16x8*)(ss + (size_t)(shb + c) * 16384 + b * HW + hw);
        float xv[8] = {x0.x, x0.y, x0.z, x0.w, x1.x, x1.y, x1.z, x1.w};
        #pragma unroll
        for (int k = 0; k < 8; k++) {
            int w = wseg * 8 + k;
            float v = (xv[k] - mu) * rsig * (1.f + (float)scv[k]) + (float)shv[k];
            tl[w >> 1][cl * 4 + hh * 2 + (w & 1)] = (bf16)v;
        }
    }
    __syncthreads();
    int token = tid >> 3, seg = (tid & 7) * 16;
    bf16* drow = dst + ((size_t)(b * seqstride + tokoff + n1 * 32 + token)) * DD + c0 * 4 + seg;
    *(bf16x8*)drow = *(const bf16x8*)&tl[token][seg];
    *(bf16x8*)(drow + 8) = *(const bf16x8*)&tl[token][seg + 8];
}

__global__ __launch_bounds__(256) void copy_gt(const float* __restrict__ gtok, const float* __restrict__ ttok,
                                               bf16* __restrict__ T) {
    int which = blockIdx.x, b = blockIdx.y;
    const float* src = (which == 0 ? gtok : ttok) + b * DD;
    bf16* dst = T + (size_t)(b * SEQ + which) * DD;
    for (int d = threadIdx.x; d < DD; d += 256) dst[d] = (bf16)src[d];
}

// ---------------------------------------------------------------------------
// attention: vk[e][d] = sum_s vpad[s,e]*k[s,d]; grid 144*4 (s-split, atomics)
__global__ __launch_bounds__(256) void attn_vk(const bf16* __restrict__ qkv, float* __restrict__ vk) {
    int bh = blockIdx.x >> 2, sb = blockIdx.x & 3;
    int b = bh / 36, h = bh % 36;
    int s_begin = sb * 288;
    int s_end = min(s_begin + 288, SEQ);
    const bf16* kbase = qkv + (size_t)(DD + h * 32) * RTOT + b * SEQ;
    const bf16* vbase = qkv + (size_t)(2 * DD + h * 32) * RTOT + b * SEQ;
    __shared__ __align__(16) bf16 kk[32][80];
    __shared__ __align__(16) bf16 vv[32][80];
    int tid = threadIdx.x;
    int e = tid >> 3, dg = (tid & 7) * 4;
    int lrow = tid >> 3, lcol = (tid & 7) * 8;
    float a0 = 0.f, a1 = 0.f, a2 = 0.f, a3 = 0.f, aD = 0.f;
    for (int s0 = s_begin; s0 < s_end; s0 += 64) {
        __syncthreads();
        #pragma unroll
        for (int j = 0; j < 8; j++) {
            int s = s0 + lcol + j;
            bool ok = s < s_end;
            kk[lrow][lcol + j] = ok ? kbase[(size_t)lrow * RTOT + s] : (bf16)0.f;
            vv[lrow][lcol + j] = ok ? vbase[(size_t)lrow * RTOT + s] : (bf16)0.f;
        }
        __syncthreads();
        #pragma unroll
        for (int j0 = 0; j0 < 64; j0 += 8) {
            bf16x8 vvv = *(const bf16x8*)&vv[e][j0];
            bf16x8 k0 = *(const bf16x8*)&kk[dg + 0][j0];
            bf16x8 k1 = *(const bf16x8*)&kk[dg + 1][j0];
            bf16x8 k2 = *(const bf16x8*)&kk[dg + 2][j0];
            bf16x8 k3 = *(const bf16x8*)&kk[dg + 3][j0];
            #pragma unroll
            for (int j = 0; j < 8; j++) {
                float vf = (float)vvv[j];
                a0 += vf * (float)k0[j];
                a1 += vf * (float)k1[j];
                a2 += vf * (float)k2[j];
                a3 += vf * (float)k3[j];
            }
            if (tid < 32) {
                bf16x8 kd = *(const bf16x8*)&kk[tid][j0];
                #pragma unroll
                for (int j = 0; j < 8; j++) aD += (float)kd[j];
            }
        }
    }
    float* dst = vk + (size_t)bh * 1056;
    atomicAdd(&dst[e * 32 + dg + 0], a0);
    atomicAdd(&dst[e * 32 + dg + 1], a1);
    atomicAdd(&dst[e * 32 + dg + 2], a2);
    atomicAdd(&dst[e * 32 + dg + 3], a3);
    if (tid < 32) atomicAdd(&dst[1024 + tid], aD);
}

__global__ __launch_bounds__(256) void attn_out(const bf16* __restrict__ qkv, const float* __restrict__ vk,
                                                bf16* __restrict__ att) {
    int bh = blockIdx.y, b = bh / 36, h = bh % 36;
    int s0 = blockIdx.x * 64;
    __shared__ float vks[1056];
    __shared__ __align__(16) bf16 qs[32][80];
    int tid = threadIdx.x;
    for (int i = tid; i < 1056; i += 256) vks[i] = vk[(size_t)bh * 1056 + i];
    const bf16* qbase = qkv + (size_t)(h * 32) * RTOT + b * SEQ;
    int lrow = tid >> 3, lcol = (tid & 7) * 8;
    #pragma unroll
    for (int j = 0; j < 8; j++) {
        int s = s0 + lcol + j;
        qs[lrow][lcol + j] = (s < SEQ) ? qbase[(size_t)lrow * RTOT + s] : (bf16)0.f;
    }
    __syncthreads();
    int sl = tid >> 2, eg = (tid & 3) * 8;
    int s = s0 + sl;
    float num[8] = {0.f, 0.f, 0.f, 0.f, 0.f, 0.f, 0.f, 0.f};
    float den = 0.f;
    #pragma unroll
    for (int d = 0; d < 32; d++) {
        float qv = (float)qs[d][sl];
        den += vks[1024 + d] * qv;
        #pragma unroll
        for (int t = 0; t < 8; t++) num[t] += vks[(eg + t) * 32 + d] * qv;
    }
    if (s < SEQ) {
        float inv = 1.f / (den + 1e-8f);
        bf16* dst = att + ((size_t)(b * SEQ + s)) * DD + h * 32 + eg;
        #pragma unroll
        for (int t = 0; t < 8; t++) dst[t] = (bf16)(num[t] * inv);
    }
}

// ---------------------------------------------------------------------------
__global__ __launch_bounds__(256) void add_attn(const float* __restrict__ x, const bf16* __restrict__ aproj,
                                                const bf16* __restrict__ ss, float* __restrict__ xo,
                                                float* __restrict__ part) {
    int b = blockIdx.x / 4608;
    size_t idx = (size_t)blockIdx.x * 256 + threadIdx.x;
    size_t local = idx - (size_t)b * NPB;
    int c = (int)(local >> 12), hw = (int)(local & 4095);
    int hh = hw >> 6, w = hw & 63;
    int n = (hh >> 1) * 32 + (w >> 1);
    int dd = c * 4 + (hh & 1) * 2 + (w & 1);
    float a = (float)aproj[(size_t)dd * RTOT + b * SEQ + 2 + n];
    float g = (float)ss[(size_t)(576 + c) * 16384 + b * HW + hw];
    float v = x[idx] + a * g;
    xo[idx] = v;
    block_reduce2_store(v, v * v, part + (size_t)blockIdx.x * 2);
}

// ---------------------------------------------------------------------------
// depthwise 3x3 + bias + GLU. grid (72 cchunk, 16 tile, 4 b), block 256.
// R9: staging vectorized bf16x8 (was scalar bf16 loads).
__global__ __launch_bounds__(256) void dwglu(const bf16* __restrict__ y, const float* __restrict__ dw_w,
                                             const float* __restrict__ dw_b, bf16* __restrict__ g) {
    __shared__ __align__(16) bf16 xs[6400];
    __shared__ __align__(16) bf16 gs[6400];
    int b = blockIdx.z, tile = blockIdx.y, c0 = blockIdx.x * 64;
    int ty = (tile >> 2) * 8, tx = (tile & 3) * 8;
    int tid = threadIdx.x, cc = tid & 63, pg = tid >> 6;
    int pos8 = tid >> 3, cseg = (tid & 7) * 8;
    bf16x8 z = {(bf16)0.f, (bf16)0.f, (bf16)0.f, (bf16)0.f,
                (bf16)0.f, (bf16)0.f, (bf16)0.f, (bf16)0.f};
    #pragma unroll
    for (int p0 = 0; p0 < 128; p0 += 32) {
        int p = p0 + pos8;
        if (p < 100) {
            int py = ty + p / 10 - 1, px = tx + p % 10 - 1;
            bool in = (py >= 0 && py < 32 && px >= 0 && px < 32);
            bf16x8 xv = z, gv = z;
            if (in) {
                size_t base = ((size_t)(b * NTOK + py * 32 + px)) * HF2 + c0 + cseg;
                xv = *(const bf16x8*)&y[base];
                gv = *(const bf16x8*)&y[base + HF];
            }
            *(bf16x8*)&xs[p * 64 + cseg] = xv;
            *(bf16x8*)&gs[p * 64 + cseg] = gv;
        }
    }
    float wx[9], wg[9];
    #pragma unroll
    for (int t = 0; t < 9; t++) {
        wx[t] = dw_w[(size_t)(c0 + cc) * 9 + t];
        wg[t] = dw_w[(size_t)(HF + c0 + cc) * 9 + t];
    }
    float bx = dw_b[c0 + cc], bg = dw_b[HF + c0 + cc];
    __syncthreads();
    for (int p = pg * 16; p < pg * 16 + 16; p++) {
        int py = p >> 3, px = p & 7;
        float ax = bx, ag = bg;
        #pragma unroll
        for (int dy = 0; dy < 3; dy++)
            #pragma unroll
            for (int dx = 0; dx < 3; dx++) {
                int q = (py + dy) * 10 + (px + dx);
                ax += (float)xs[q * 64 + cc] * wx[dy * 3 + dx];
                ag += (float)gs[q * 64 + cc] * wg[dy * 3 + dx];
            }
        float out = ax * (ag / (1.f + __expf(-ag)));
        g[((size_t)(b * NTOK + (ty + py) * 32 + tx + px)) * HF + c0 + cc] = (bf16)out;
    }
}

// final: out = x1 + comb(m)*g_mlp
__global__ __launch_bounds__(256) void add_mlp(const bf16* __restrict__ mm, const bf16* __restrict__ ss,
                                               float* __restrict__ xo) {
    int b = blockIdx.x / 4608;
    size_t idx = (size_t)blockIdx.x * 256 + threadIdx.x;
    size_t local = idx - (size_t)b * NPB;
    int c = (int)(local >> 12), hw = (int)(local & 4095);
    int hh = hw >> 6, w = hw & 63;
    int n = (hh >> 1) * 32 + (w >> 1);
    int dd = c * 4 + (hh & 1) * 2 + (w & 1);
    float mv = (float)mm[(size_t)dd * 4096 + b * NTOK + n];
    float g = (float)ss[(size_t)(1440 + c) * 16384 + b * HW + hw];
    xo[idx] = xo[idx] + mv * g;
}

// ---------------------------------------------------------------------------
extern "C" void kernel_launch(void* const* d_in, const int* in_sizes, int n_in,
                              void* d_out, int out_size, void* d_ws, size_t ws_size,
                              hipStream_t stream) {
    (void)in_sizes; (void)n_in; (void)out_size; (void)ws_size;
    const float* x      = (const float*)d_in[0];
    const float* cond   = (const float*)d_in[1];
    const float* gtok   = (const float*)d_in[2];
    const float* ttok   = (const float*)d_in[3];
    const float* ss_w   = (const float*)d_in[4];
    const float* ss_b   = (const float*)d_in[5];
    const float* qkv_w  = (const float*)d_in[6];
    const float* proj_w = (const float*)d_in[7];
    const float* proj_b = (const float*)d_in[8];
    const float* inv_w  = (const float*)d_in[9];
    const float* inv_b  = (const float*)d_in[10];
    const float* dw_w   = (const float*)d_in[11];
    const float* dw_b   = (const float*)d_in[12];
    const float* pw_w   = (const float*)d_in[13];
    float* out = (float*)d_out;
    char* ws = (char*)d_ws;

    float* sums  = (float*)(ws + OFF_SUMS);
    float* PART1 = (float*)(ws + OFF_PART1);
    float* PART2 = (float*)(ws + OFF_PART2);
    bf16* SS    = (bf16*)(ws + OFF_SS);
    bf16* A1    = (bf16*)(ws + OFF_A1);
    bf16* T     = (bf16*)(ws + OFF_T);
    bf16* QKV   = (bf16*)(ws + OFF_QKV);
    float* VK   = (float*)(ws + OFF_VK);
    bf16* ATT   = (bf16*)(ws + OFF_ATT);
    bf16* APROJ = (bf16*)(ws + OFF_APROJ);
    bf16* T2    = (bf16*)(ws + OFF_T2);
    bf16* Y     = (bf16*)(ws + OFF_Y);
    bf16* G     = (bf16*)(ws + OFF_G);
    bf16* MM    = (bf16*)(ws + OFF_M);
    bf16* WSS   = (bf16*)(ws + OFF_WSS);
    bf16* WQKV  = (bf16*)(ws + OFF_WQKV);
    bf16* WPROJ = (bf16*)(ws + OFF_WPROJ);
    bf16* WINV  = (bf16*)(ws + OFF_WINV);
    bf16* WPW   = (bf16*)(ws + OFF_WPW);

    cvt_bf16<<<2916, 256, 0, stream>>>(ss_w, WSS, C6 * C6 / 4);
    cvt_bf16<<<3888, 256, 0, stream>>>(qkv_w, WQKV, 3456 * DD / 4);
    cvt_bf16<<<1296, 256, 0, stream>>>(proj_w, WPROJ, DD * DD / 4);
    cvt_bf16<<<10368, 256, 0, stream>>>(inv_w, WINV, HF2 * DD / 4);
    cvt_bf16<<<5184, 256, 0, stream>>>(pw_w, WPW, DD * HF / 4);

    ln_stats<<<1152, 256, 0, stream>>>(x, PART1);
    reduce_part<<<4, 256, 0, stream>>>(PART1, sums, 288, 0);
    prep_cond<<<dim3(64, 27, 4), 256, 0, stream>>>(cond, A1);
    // ss = silu(cond) @ ss_w^T + ss_b, out [o][16384]  (256^2 8-wave kernel)
    gemm256<0, 1><<<dim3(64, 7), 512, 0, stream>>>(WSS, A1, ss_b, SS, C6, 16384, C6, 0);
    build_tok_t<<<dim3(9, 32, 4), 256, 0, stream>>>(x, SS, sums, 0, 0, 288, T, 2, SEQ);
    copy_gt<<<dim3(2, 4), 256, 0, stream>>>(gtok, ttok, T);
    // qkv, relu on first 2304 output channels
    gemm256<1, 0><<<dim3(17, 14), 512, 0, stream>>>(WQKV, T, nullptr, QKV, 3456, RTOT, DD, 2304);
    hipMemsetAsync(ws + OFF_VK, 0, (size_t)144 * 1056 * 4, stream);
    attn_vk<<<576, 256, 0, stream>>>(QKV, VK);
    attn_out<<<dim3(17, 144), 256, 0, stream>>>(QKV, VK, ATT);
    // proj (small grid -> 128^2 kernel)
    gemm_bt<0, 1><<<dim3(33, 9), 256, 0, stream>>>(WPROJ, ATT, proj_b, APROJ, DD, RTOT, DD, 0);
    add_attn<<<18432, 256, 0, stream>>>(x, APROJ, SS, out, PART2);
    reduce_part<<<4, 256, 0, stream>>>(PART2, sums, 4608, 8);
    build_tok_t<<<dim3(9, 32, 4), 256, 0, stream>>>(out, SS, sums, 8, 864, 1152, T2, 0, 1024);
    // MLP expand + silu, out [r][9216]
    gemm256<2, 2><<<dim3(36, 16), 512, 0, stream>>>(T2, WINV, inv_b, Y, 4096, HF2, DD, 0);
    dwglu<<<dim3(72, 16, 4), 256, 0, stream>>>(Y, dw_w, dw_b, G);
    // MLP project, out [o][4096] (small grid -> 128^2 kernel)
    gemm_bt<0, 0><<<dim3(32, 9), 256, 0, stream>>>(WPW, G, nullptr, MM, DD, 4096, HF, 0);
    add_mlp<<<18432, 256, 0, stream>>>(MM, SS, out);
}

// Round 6
// 1014.777 us; speedup vs baseline: 1.0494x; 1.0494x over previous
//
#include <hip/hip_runtime.h>
#include <hip/hip_bf16.h>
#include <cstdint>

// ---------------------------------------------------------------------------
// SANA MS-AdaLN block on MI355X.
// R1: LN stats via per-block partials. R4: LDS-DMA fill conflicts structural.
// R5a/R6: GROUP_M + XCD-chunked bijective swizzle (FETCH 401->95 MB).
// R7: 2-phase dbuf + counted vmcnt: VALUBusy 39->16, MfmaUtil 23->26.
// R8: 2-deep prefetch: NEUTRAL. 128²/BK=32 is structure-bound (m97 ceiling).
// R9/R10: gemm256 256²/BK=64/8-wave, XOR swizzle (bank conflicts 12.4M -> 0!)
//   but 8 pinned phases (sched_barrier + lgkmcnt-before-barrier + fences at
//   every boundary) serialized each phase: MfmaUtil 15.5%, 224 µs (m141-class
//   order-pinning regression).
// R11: same geometry, TWO scheduling regions per K-tile (2 barriers, was 8):
//   phaseA {ds af(q0)+bv(16 reads) || stage A(t+1)->As[oth] || 32 MFMA},
//   phaseB {ds af(q1) || stage B(t+2)->Bs[cur] || vmcnt(4) || 32 MFMA}.
//   No manual lgkmcnt, no sched_barrier: compiler interleaves reads/waits/
//   MFMAs within each region (the R7/R8-proven pattern, bigger regions).
//   Race-audited: B stage after bv fully consumed (phaseA barrier); A stage
//   into the buffer freed by t-1's phaseB barrier; vmcnt(4) retires exactly
//   {B(t+1),A(t+1)} before the barrier preceding tile t+1's reads.
// ---------------------------------------------------------------------------

typedef __bf16 bf16;
typedef bf16 bf16x8 __attribute__((ext_vector_type(8)));
typedef bf16 bf16x4 __attribute__((ext_vector_type(4)));
typedef float f32x4 __attribute__((ext_vector_type(4)));

typedef const __attribute__((address_space(1))) void gas_void;
typedef __attribute__((address_space(3))) void las_void;

__device__ __forceinline__ void gload16(const bf16* g, bf16* l) {
    __builtin_amdgcn_global_load_lds((gas_void*)g, (las_void*)l, 16, 0, 0);
}

// ---- problem constants ----
#define BB 4
#define CC 288
#define HW 4096          // 64*64
#define C6 1728
#define DD 1152
#define SEQ 1026
#define RTOT 4104        // 4*1026
#define NTOK 1024
#define HF 4608
#define HF2 9216
#define NPB 1179648      // elements per batch sample (288*4096)

// ---- workspace layout (bytes) ----
static constexpr size_t OFF_SUMS = 0;                                   // 16 floats
static constexpr size_t OFF_SS   = 256;                                 // bf16 [1728][16384]
static constexpr size_t SS_BYTES = (size_t)C6 * 16384 * 2;              // 56,623,104
static constexpr size_t OFF_R2   = OFF_SS + SS_BYTES;
// phase A
static constexpr size_t OFF_PART1= OFF_R2;                              // f32 [1152][2]
static constexpr size_t OFF_A1   = OFF_R2;                              // bf16 [16384][1728]
// phase B
static constexpr size_t OFF_T    = OFF_R2;                              // bf16 [4104][1152]
static constexpr size_t OFF_QKV  = OFF_T   + (size_t)RTOT*DD*2;         // bf16 [3456][4104]
static constexpr size_t OFF_PART2= OFF_QKV;                             // f32 [18432][2]
static constexpr size_t OFF_VK   = OFF_QKV + (size_t)3456*RTOT*2;       // f32  [144][1056]
static constexpr size_t OFF_ATT  = OFF_VK  + (size_t)144*1056*4;        // bf16 [4104][1152]
static constexpr size_t OFF_APROJ= OFF_ATT + (size_t)RTOT*DD*2;         // bf16 [1152][4104]
// phase C
static constexpr size_t OFF_T2   = OFF_R2;                              // bf16 [4096][1152]
static constexpr size_t OFF_Y    = OFF_T2  + (size_t)4096*DD*2;         // bf16 [4096][9216]
static constexpr size_t OFF_G    = OFF_Y   + (size_t)4096*HF2*2;        // bf16 [4096][4608]
static constexpr size_t OFF_M    = OFF_G   + (size_t)4096*HF*2;         // bf16 [1152][4096]
// converted weights (persistent)
static constexpr size_t OFF_W    = OFF_R2  + 132120576;
static constexpr size_t OFF_WSS  = OFF_W;
static constexpr size_t OFF_WQKV = OFF_WSS  + (size_t)C6*C6*2;
static constexpr size_t OFF_WPROJ= OFF_WQKV + (size_t)3456*DD*2;
static constexpr size_t OFF_WINV = OFF_WPROJ+ (size_t)DD*DD*2;
static constexpr size_t OFF_WPW  = OFF_WINV + (size_t)HF2*DD*2;

// ---------------------------------------------------------------------------
// fp32 -> bf16 weight conversion
__global__ __launch_bounds__(256) void cvt_bf16(const float* __restrict__ s,
                                                bf16* __restrict__ d, int n4) {
    int i = blockIdx.x * 256 + threadIdx.x;
    if (i < n4) {
        float4 v = ((const float4*)s)[i];
        bf16x4 o = {(bf16)v.x, (bf16)v.y, (bf16)v.z, (bf16)v.w};
        ((bf16x4*)d)[i] = o;
    }
}

// ---------------------------------------------------------------------------
__device__ __forceinline__ void block_reduce2_store(float s1, float s2, float* dst) {
    #pragma unroll
    for (int o = 32; o > 0; o >>= 1) { s1 += __shfl_down(s1, o); s2 += __shfl_down(s2, o); }
    __shared__ float r1[4], r2[4];
    int wave = threadIdx.x >> 6, lane = threadIdx.x & 63;
    if (lane == 0) { r1[wave] = s1; r2[wave] = s2; }
    __syncthreads();
    if (threadIdx.x == 0) {
        dst[0] = r1[0] + r1[1] + r1[2] + r1[3];
        dst[1] = r2[0] + r2[1] + r2[2] + r2[3];
    }
}

__global__ __launch_bounds__(256) void ln_stats(const float* __restrict__ x, float* __restrict__ part) {
    const float* base = x + (size_t)blockIdx.x * 4096;
    float s1 = 0.f, s2 = 0.f;
    #pragma unroll
    for (int it = 0; it < 4; it++) {
        float4 v = ((const float4*)base)[it * 256 + threadIdx.x];
        s1 += v.x + v.y + v.z + v.w;
        s2 += v.x * v.x + v.y * v.y + v.z * v.z + v.w * v.w;
    }
    block_reduce2_store(s1, s2, part + (size_t)blockIdx.x * 2);
}

__global__ __launch_bounds__(256) void reduce_part(const float* __restrict__ part, float* __restrict__ sums,
                                                   int nper, int out_off) {
    int b = blockIdx.x;
    float s1 = 0.f, s2 = 0.f;
    for (int i = threadIdx.x; i < nper; i += 256) {
        s1 += part[(size_t)(b * nper + i) * 2];
        s2 += part[(size_t)(b * nper + i) * 2 + 1];
    }
    block_reduce2_store(s1, s2, sums + out_off + b * 2);
}

// ---------------------------------------------------------------------------
// silu(cond) transpose: (b, k, hw) f32 -> A1[(b,hw)][k] bf16. grid (64,27,4)
__global__ __launch_bounds__(256) void prep_cond(const float* __restrict__ cond, bf16* __restrict__ A1) {
    __shared__ float tile[64][65];
    int b = blockIdx.z, k0 = blockIdx.y * 64, h0 = blockIdx.x * 64;
    int col = threadIdx.x & 63, r4 = threadIdx.x >> 6;
    const float* src = cond + ((size_t)b * C6 + k0) * HW + h0;
    #pragma unroll
    for (int p = 0; p < 16; p++) {
        int kk = r4 + p * 4;
        float v = src[(size_t)kk * HW + col];
        tile[col][kk] = v / (1.f + __expf(-v));
    }
    __syncthreads();
    bf16* dst = A1 + ((size_t)(b * HW + h0)) * C6 + k0;
    #pragma unroll
    for (int p = 0; p < 16; p++) {
        int rr = r4 + p * 4;
        dst[(size_t)rr * C6 + col] = (bf16)tile[rr][col];
    }
}

// ---------------------------------------------------------------------------
// gemm256: 256x256 tile, BK=64, 512 threads (8 waves, 2Mx4N), dbuf LDS,
// 2 scheduling regions per K-tile (R11). C[m][n]=sum_k A[m][k]B[n][k].
template <int EP, int BIAS>
__global__ __launch_bounds__(512, 2) void gemm256(const bf16* __restrict__ A, const bf16* __restrict__ B,
                                                  const float* __restrict__ bias, bf16* __restrict__ C,
                                                  int M, int N, int K, int reluLimit) {
    __shared__ __align__(16) bf16 As[2][256 * 64];
    __shared__ __align__(16) bf16 Bs[2][256 * 64];
    const int tid = threadIdx.x, wave = tid >> 6, lane = tid & 63;

    // ---- XCD-chunked GROUP_M grid swizzle (bijection over the grid) ----
    const int nx = gridDim.x, ny = gridDim.y, G = 8;
    int idx = blockIdx.y * nx + blockIdx.x;
    int total = nx * ny;
    int q = total >> 3, rm = total & 7;
    int xcd = idx & 7, slot = idx >> 3;
    int vid = (xcd < rm ? xcd * (q + 1) : rm * (q + 1) + (xcd - rm) * q) + slot;
    int band = vid / (G * nx);
    int r = vid - band * (G * nx);
    int gm = min(G, ny - band * G);
    const int m0 = (band * G + r % gm) * 256;
    const int n0 = (r / gm) * 256;

    // ---- staging: per-wave gload_lds writes 1KB linear (base + lane*16).
    // lane covers row = wave*8 + (lane>>3) (+64*rr +128*half), kchunk=(lane&7).
    // Source pre-swizzled: kchunk ^= (row&7) (involution; read applies same).
    const int srow_l = (wave << 3) + (lane >> 3);            // 0..63
    const int sk_el  = (((lane & 7) ^ (lane >> 3)) << 3);    // swizzled k element
    const bf16* pA[4]; const bf16* pB[4];
    #pragma unroll
    for (int g = 0; g < 4; ++g) {
        pA[g] = A + (size_t)min(m0 + g * 64 + srow_l, M - 1) * K + sk_el;
        pB[g] = B + (size_t)min(n0 + g * 64 + srow_l, N - 1) * K + sk_el;
    }
    auto STAGE_A = [&](int buf, int half) {
        #pragma unroll
        for (int rr = 0; rr < 2; ++rr) {
            gload16(pA[half * 2 + rr], &As[buf][half * 8192 + rr * 4096 + (wave << 9)]);
            pA[half * 2 + rr] += 64;
        }
    };
    auto STAGE_B = [&](int buf, int half) {
        #pragma unroll
        for (int rr = 0; rr < 2; ++rr) {
            gload16(pB[half * 2 + rr], &Bs[buf][half * 8192 + rr * 4096 + (wave << 9)]);
            pB[half * 2 + rr] += 64;
        }
    };

    // ---- fragment reads (swizzled to match staged layout) ----
    const int wm_w = (wave >> 2) * 128, wn_w = (wave & 3) * 64;
    const int l15 = lane & 15;
    const int fswz = (l15 & 7) << 4;          // (row&7)*16 bytes
    const int rk16 = (lane >> 4) << 4;        // 0,16,32,48 (k chunk bytes)

    bf16x8 af[8], bv[8];
    f32x4 acc[8][4];
    #pragma unroll
    for (int i = 0; i < 8; i++)
        #pragma unroll
        for (int j = 0; j < 4; j++) acc[i][j] = (f32x4){0.f, 0.f, 0.f, 0.f};

    auto LDA = [&](const bf16* base, int qm) {
        #pragma unroll
        for (int il = 0; il < 4; ++il)
            #pragma unroll
            for (int ks = 0; ks < 2; ++ks) {
                int row = wm_w + (qm * 4 + il) * 16 + l15;
                int kb  = (ks * 64 + rk16) ^ fswz;
                af[il * 2 + ks] = *(const bf16x8*)(base + row * 64 + (kb >> 1));
            }
    };
    auto LDB = [&](const bf16* base) {
        #pragma unroll
        for (int j = 0; j < 4; ++j)
            #pragma unroll
            for (int ks = 0; ks < 2; ++ks) {
                int row = wn_w + j * 16 + l15;
                int kb  = (ks * 64 + rk16) ^ fswz;
                bv[j * 2 + ks] = *(const bf16x8*)(base + row * 64 + (kb >> 1));
            }
    };
    auto MFQ = [&](int qm) {
        __builtin_amdgcn_s_setprio(1);
        #pragma unroll
        for (int il = 0; il < 4; ++il)
            #pragma unroll
            for (int j = 0; j < 4; ++j)
                #pragma unroll
                for (int ks = 0; ks < 2; ++ks)
                    acc[qm * 4 + il][j] = __builtin_amdgcn_mfma_f32_16x16x32_bf16(
                        af[il * 2 + ks], bv[j * 2 + ks], acc[qm * 4 + il][j], 0, 0, 0);
        __builtin_amdgcn_s_setprio(0);
    };

    const int nt = K >> 6;                     // 27 / 18 (all >= 4)
    // prologue: stage tiles 0 and 1 fully; retire tile 0 (vmcnt(8) leaves
    // tile 1's 8 loads in flight).
    STAGE_B(0, 0); STAGE_B(0, 1); STAGE_A(0, 0); STAGE_A(0, 1);
    STAGE_B(1, 0); STAGE_B(1, 1); STAGE_A(1, 0); STAGE_A(1, 1);
    asm volatile("s_waitcnt vmcnt(8)" ::: "memory");
    __builtin_amdgcn_s_barrier();
    asm volatile("" ::: "memory");

    for (int t = 0; t < nt; ++t) {
        const int cur = t & 1, oth = cur ^ 1;
        const bf16* Ab = &As[cur][0];
        const bf16* Bb = &Bs[cur][0];
        // ---- region A: reads for row-half 0 + all B; stage A(t+1); 32 MFMA.
        LDA(Ab, 0);
        LDB(Bb);
        if (t >= 1 && t + 1 < nt) { STAGE_A(oth, 0); STAGE_A(oth, 1); }  // A(t+1)->As[oth]
        MFQ(0);
        asm volatile("" ::: "memory");
        __builtin_amdgcn_s_barrier();          // all bv/af(q0) reads consumed
        asm volatile("" ::: "memory");
        // ---- region B: reads row-half 1; stage B(t+2); counted vmcnt; 32 MFMA.
        LDA(Ab, 1);
        if (t + 2 < nt) {
            STAGE_B(cur, 0); STAGE_B(cur, 1);                            // B(t+2)->Bs[cur]
            asm volatile("s_waitcnt vmcnt(4)" ::: "memory");             // retire B(t+1),A(t+1)
        } else if (t + 2 == nt) {
            asm volatile("s_waitcnt vmcnt(0)" ::: "memory");             // retire B(nt-1),A(nt-1)
        }
        MFQ(1);
        asm volatile("" ::: "memory");
        __builtin_amdgcn_s_barrier();          // tile t fully consumed; t+1 landed
        asm volatile("" ::: "memory");
    }

    // epilogue
    const int mq = (lane >> 4) * 4, nl = lane & 15;
    #pragma unroll
    for (int i = 0; i < 8; i++) {
        #pragma unroll
        for (int j = 0; j < 4; j++) {
            int n = n0 + wn_w + j * 16 + nl;
            if (n < N) {
                #pragma unroll
                for (int r2 = 0; r2 < 4; r2++) {
                    int m = m0 + wm_w + i * 16 + mq + r2;
                    if (m < M) {
                        float v = acc[i][j][r2];
                        if (BIAS == 1) v += bias[m];
                        else if (BIAS == 2) v += bias[n];
                        if (EP == 1) { if (m < reluLimit) v = fmaxf(v, 0.f); }
                        else if (EP == 2) { v = v / (1.f + __expf(-v)); }
                        C[(size_t)m * N + n] = (bf16)v;
                    }
                }
            }
        }
    }
}

// ---------------------------------------------------------------------------
// gemm_bt (128x128, R8 structure): kept for small-grid GEMMs (proj/project).
template <int EP, int BIAS>
__global__ __launch_bounds__(256) void gemm_bt(const bf16* __restrict__ A, const bf16* __restrict__ B,
                                               const float* __restrict__ bias, bf16* __restrict__ C,
                                               int M, int N, int K, int reluLimit) {
    __shared__ __align__(16) bf16 As[3][128 * 32];
    __shared__ __align__(16) bf16 Bs[3][128 * 32];
    const int tid = threadIdx.x, wave = tid >> 6, lane = tid & 63;

    const int nx = gridDim.x, ny = gridDim.y, G = 8;
    int idx = blockIdx.y * nx + blockIdx.x;
    int total = nx * ny;
    int q = total >> 3, rm = total & 7;
    int xcd = idx & 7, slot = idx >> 3;
    int vid = (xcd < rm ? xcd * (q + 1) : rm * (q + 1) + (xcd - rm) * q) + slot;
    int band = vid / (G * nx);
    int r = vid - band * (G * nx);
    int gm = min(G, ny - band * G);
    const int m0 = (band * G + r % gm) * 128;
    const int n0 = (r / gm) * 128;

    const int c0 = wave * 128 + lane;
    const int c1 = c0 + 64;
    const int sw = ((c0 >> 2) & 3) ^ ((c0 >> 4) & 3);
    const int ka = (((c0 & 3) ^ sw)) * 8;
    int ra0 = min(m0 + (c0 >> 2), M - 1), ra1 = min(m0 + (c1 >> 2), M - 1);
    int rb0 = min(n0 + (c0 >> 2), N - 1), rb1 = min(n0 + (c1 >> 2), N - 1);
    const bf16* gA0 = A + (size_t)ra0 * K + ka;
    const bf16* gA1 = A + (size_t)ra1 * K + ka;
    const bf16* gB0 = B + (size_t)rb0 * K + ka;
    const bf16* gB1 = B + (size_t)rb1 * K + ka;

    const int wm = (wave >> 1) * 64, wn = (wave & 1) * 64;
    const int l15 = lane & 15;
    const int sr = (l15 & 3) ^ ((l15 >> 2) & 3);
    const int fc = ((lane >> 4) ^ sr) * 8;
    const int fao = (wm + l15) * 32 + fc;
    const int fbo = (wn + l15) * 32 + fc;
    const int lwo = wave * 1024;

    f32x4 acc[4][4];
    #pragma unroll
    for (int i = 0; i < 4; i++)
        #pragma unroll
        for (int j = 0; j < 4; j++) acc[i][j] = (f32x4){0.f, 0.f, 0.f, 0.f};

    auto STAGE = [&](int buf) {
        gload16(gA0, &As[buf][lwo]);
        gload16(gA1, &As[buf][lwo + 512]);
        gload16(gB0, &Bs[buf][lwo]);
        gload16(gB1, &Bs[buf][lwo + 512]);
        gA0 += 32; gA1 += 32; gB0 += 32; gB1 += 32;
    };
    auto COMP = [&](int buf) {
        const bf16* fa = &As[buf][fao];
        const bf16* fb = &Bs[buf][fbo];
        bf16x8 af[4], bvv[4];
        #pragma unroll
        for (int i = 0; i < 4; i++) af[i] = *(const bf16x8*)(fa + i * 16 * 32);
        #pragma unroll
        for (int j = 0; j < 4; j++) bvv[j] = *(const bf16x8*)(fb + j * 16 * 32);
        #pragma unroll
        for (int i = 0; i < 4; i++)
            #pragma unroll
            for (int j = 0; j < 4; j++)
                acc[i][j] = __builtin_amdgcn_mfma_f32_16x16x32_bf16(af[i], bvv[j], acc[i][j], 0, 0, 0);
    };
    auto STEP = [&](int cbuf, int sbuf) {
        STAGE(sbuf);
        asm volatile("s_waitcnt vmcnt(8)" ::: "memory");
        __builtin_amdgcn_s_barrier();
        asm volatile("" ::: "memory");
        COMP(cbuf);
        asm volatile("" ::: "memory");
        __builtin_amdgcn_s_barrier();
    };

    const int nt = K >> 5;
    STAGE(0);
    STAGE(1);
    for (int it = 0; it < nt / 3 - 1; ++it) {
        STEP(0, 2);
        STEP(1, 0);
        STEP(2, 1);
    }
    STEP(0, 2);
    asm volatile("s_waitcnt vmcnt(4)" ::: "memory");
    __builtin_amdgcn_s_barrier();
    asm volatile("" ::: "memory");
    COMP(1);
    asm volatile("" ::: "memory");
    asm volatile("s_waitcnt vmcnt(0)" ::: "memory");
    __builtin_amdgcn_s_barrier();
    asm volatile("" ::: "memory");
    COMP(2);

    const int mq = (lane >> 4) * 4, nl = lane & 15;
    #pragma unroll
    for (int i = 0; i < 4; i++) {
        #pragma unroll
        for (int j = 0; j < 4; j++) {
            int n = n0 + wn + j * 16 + nl;
            if (n < N) {
                #pragma unroll
                for (int r2 = 0; r2 < 4; r2++) {
                    int m = m0 + wm + i * 16 + mq + r2;
                    if (m < M) {
                        float v = acc[i][j][r2];
                        if (BIAS == 1) v += bias[m];
                        else if (BIAS == 2) v += bias[n];
                        if (EP == 1) { if (m < reluLimit) v = fmaxf(v, 0.f); }
                        else if (EP == 2) { v = v / (1.f + __expf(-v)); }
                        C[(size_t)m * N + n] = (bf16)v;
                    }
                }
            }
        }
    }
}

// ---------------------------------------------------------------------------
// token build (coalesced): grid (9 cchunk, 32 n1, 4 b), block 256.
__global__ __launch_bounds__(256) void build_tok_t(const float* __restrict__ xs, const bf16* __restrict__ ss,
                                                   const float* __restrict__ sums, int soff, int shb, int scb,
                                                   bf16* __restrict__ dst, int tokoff, int seqstride) {
    __shared__ bf16 tl[32][132];
    int cch = blockIdx.x, n1 = blockIdx.y, b = blockIdx.z;
    int c0 = cch * 32;
    int tid = threadIdx.x, cl = tid >> 3, wseg = tid & 7;

    float mu = sums[soff + b * 2] * (1.f / (float)NPB);
    float var = sums[soff + b * 2 + 1] * (1.f / (float)NPB) - mu * mu;
    float rsig = rsqrtf(var + 1e-6f);

    int c = c0 + cl;
    #pragma unroll
    for (int hh = 0; hh < 2; hh++) {
        int hw = (2 * n1 + hh) * 64 + wseg * 8;
        const float* xp = xs + ((size_t)b * CC + c) * HW + hw;
        float4 x0 = ((const float4*)xp)[0];
        float4 x1 = ((const float4*)xp)[1];
        bf16x8 scv = *(const bf16x8*)(ss + (size_t)(scb + c) * 16384 + b * HW + hw);
        bf16x8 shv = *(const bf16x8*)(ss + (size_t)(shb + c) * 16384 + b * HW + hw);
        float xv[8] = {x0.x, x0.y, x0.z, x0.w, x1.x, x1.y, x1.z, x1.w};
        #pragma unroll
        for (int k = 0; k < 8; k++) {
            int w = wseg * 8 + k;
            float v = (xv[k] - mu) * rsig * (1.f + (float)scv[k]) + (float)shv[k];
            tl[w >> 1][cl * 4 + hh * 2 + (w & 1)] = (bf16)v;
        }
    }
    __syncthreads();
    int token = tid >> 3, seg = (tid & 7) * 16;
    bf16* drow = dst + ((size_t)(b * seqstride + tokoff + n1 * 32 + token)) * DD + c0 * 4 + seg;
    *(bf16x8*)drow = *(const bf16x8*)&tl[token][seg];
    *(bf16x8*)(drow + 8) = *(const bf16x8*)&tl[token][seg + 8];
}

__global__ __launch_bounds__(256) void copy_gt(const float* __restrict__ gtok, const float* __restrict__ ttok,
                                               bf16* __restrict__ T) {
    int which = blockIdx.x, b = blockIdx.y;
    const float* src = (which == 0 ? gtok : ttok) + b * DD;
    bf16* dst = T + (size_t)(b * SEQ + which) * DD;
    for (int d = threadIdx.x; d < DD; d += 256) dst[d] = (bf16)src[d];
}

// ---------------------------------------------------------------------------
// attention: vk[e][d] = sum_s vpad[s,e]*k[s,d]; grid 144*4 (s-split, atomics)
__global__ __launch_bounds__(256) void attn_vk(const bf16* __restrict__ qkv, float* __restrict__ vk) {
    int bh = blockIdx.x >> 2, sb = blockIdx.x & 3;
    int b = bh / 36, h = bh % 36;
    int s_begin = sb * 288;
    int s_end = min(s_begin + 288, SEQ);
    const bf16* kbase = qkv + (size_t)(DD + h * 32) * RTOT + b * SEQ;
    const bf16* vbase = qkv + (size_t)(2 * DD + h * 32) * RTOT + b * SEQ;
    __shared__ __align__(16) bf16 kk[32][80];
    __shared__ __align__(16) bf16 vv[32][80];
    int tid = threadIdx.x;
    int e = tid >> 3, dg = (tid & 7) * 4;
    int lrow = tid >> 3, lcol = (tid & 7) * 8;
    float a0 = 0.f, a1 = 0.f, a2 = 0.f, a3 = 0.f, aD = 0.f;
    for (int s0 = s_begin; s0 < s_end; s0 += 64) {
        __syncthreads();
        #pragma unroll
        for (int j = 0; j < 8; j++) {
            int s = s0 + lcol + j;
            bool ok = s < s_end;
            kk[lrow][lcol + j] = ok ? kbase[(size_t)lrow * RTOT + s] : (bf16)0.f;
            vv[lrow][lcol + j] = ok ? vbase[(size_t)lrow * RTOT + s] : (bf16)0.f;
        }
        __syncthreads();
        #pragma unroll
        for (int j0 = 0; j0 < 64; j0 += 8) {
            bf16x8 vvv = *(const bf16x8*)&vv[e][j0];
            bf16x8 k0 = *(const bf16x8*)&kk[dg + 0][j0];
            bf16x8 k1 = *(const bf16x8*)&kk[dg + 1][j0];
            bf16x8 k2 = *(const bf16x8*)&kk[dg + 2][j0];
            bf16x8 k3 = *(const bf16x8*)&kk[dg + 3][j0];
            #pragma unroll
            for (int j = 0; j < 8; j++) {
                float vf = (float)vvv[j];
                a0 += vf * (float)k0[j];
                a1 += vf * (float)k1[j];
                a2 += vf * (float)k2[j];
                a3 += vf * (float)k3[j];
            }
            if (tid < 32) {
                bf16x8 kd = *(const bf16x8*)&kk[tid][j0];
                #pragma unroll
                for (int j = 0; j < 8; j++) aD += (float)kd[j];
            }
        }
    }
    float* dst = vk + (size_t)bh * 1056;
    atomicAdd(&dst[e * 32 + dg + 0], a0);
    atomicAdd(&dst[e * 32 + dg + 1], a1);
    atomicAdd(&dst[e * 32 + dg + 2], a2);
    atomicAdd(&dst[e * 32 + dg + 3], a3);
    if (tid < 32) atomicAdd(&dst[1024 + tid], aD);
}

__global__ __launch_bounds__(256) void attn_out(const bf16* __restrict__ qkv, const float* __restrict__ vk,
                                                bf16* __restrict__ att) {
    int bh = blockIdx.y, b = bh / 36, h = bh % 36;
    int s0 = blockIdx.x * 64;
    __shared__ float vks[1056];
    __shared__ __align__(16) bf16 qs[32][80];
    int tid = threadIdx.x;
    for (int i = tid; i < 1056; i += 256) vks[i] = vk[(size_t)bh * 1056 + i];
    const bf16* qbase = qkv + (size_t)(h * 32) * RTOT + b * SEQ;
    int lrow = tid >> 3, lcol = (tid & 7) * 8;
    #pragma unroll
    for (int j = 0; j < 8; j++) {
        int s = s0 + lcol + j;
        qs[lrow][lcol + j] = (s < SEQ) ? qbase[(size_t)lrow * RTOT + s] : (bf16)0.f;
    }
    __syncthreads();
    int sl = tid >> 2, eg = (tid & 3) * 8;
    int s = s0 + sl;
    float num[8] = {0.f, 0.f, 0.f, 0.f, 0.f, 0.f, 0.f, 0.f};
    float den = 0.f;
    #pragma unroll
    for (int d = 0; d < 32; d++) {
        float qv = (float)qs[d][sl];
        den += vks[1024 + d] * qv;
        #pragma unroll
        for (int t = 0; t < 8; t++) num[t] += vks[(eg + t) * 32 + d] * qv;
    }
    if (s < SEQ) {
        float inv = 1.f / (den + 1e-8f);
        bf16* dst = att + ((size_t)(b * SEQ + s)) * DD + h * 32 + eg;
        #pragma unroll
        for (int t = 0; t < 8; t++) dst[t] = (bf16)(num[t] * inv);
    }
}

// ---------------------------------------------------------------------------
__global__ __launch_bounds__(256) void add_attn(const float* __restrict__ x, const bf16* __restrict__ aproj,
                                                const bf16* __restrict__ ss, float* __restrict__ xo,
                                                float* __restrict__ part) {
    int b = blockIdx.x / 4608;
    size_t idx = (size_t)blockIdx.x * 256 + threadIdx.x;
    size_t local = idx - (size_t)b * NPB;
    int c = (int)(local >> 12), hw = (int)(local & 4095);
    int hh = hw >> 6, w = hw & 63;
    int n = (hh >> 1) * 32 + (w >> 1);
    int dd = c * 4 + (hh & 1) * 2 + (w & 1);
    float a = (float)aproj[(size_t)dd * RTOT + b * SEQ + 2 + n];
    float g = (float)ss[(size_t)(576 + c) * 16384 + b * HW + hw];
    float v = x[idx] + a * g;
    xo[idx] = v;
    block_reduce2_store(v, v * v, part + (size_t)blockIdx.x * 2);
}

// ---------------------------------------------------------------------------
// depthwise 3x3 + bias + GLU. grid (72 cchunk, 16 tile, 4 b), block 256.
__global__ __launch_bounds__(256) void dwglu(const bf16* __restrict__ y, const float* __restrict__ dw_w,
                                             const float* __restrict__ dw_b, bf16* __restrict__ g) {
    __shared__ __align__(16) bf16 xs[6400];
    __shared__ __align__(16) bf16 gs[6400];
    int b = blockIdx.z, tile = blockIdx.y, c0 = blockIdx.x * 64;
    int ty = (tile >> 2) * 8, tx = (tile & 3) * 8;
    int tid = threadIdx.x, cc = tid & 63, pg = tid >> 6;
    int pos8 = tid >> 3, cseg = (tid & 7) * 8;
    bf16x8 z = {(bf16)0.f, (bf16)0.f, (bf16)0.f, (bf16)0.f,
                (bf16)0.f, (bf16)0.f, (bf16)0.f, (bf16)0.f};
    #pragma unroll
    for (int p0 = 0; p0 < 128; p0 += 32) {
        int p = p0 + pos8;
        if (p < 100) {
            int py = ty + p / 10 - 1, px = tx + p % 10 - 1;
            bool in = (py >= 0 && py < 32 && px >= 0 && px < 32);
            bf16x8 xv = z, gv = z;
            if (in) {
                size_t base = ((size_t)(b * NTOK + py * 32 + px)) * HF2 + c0 + cseg;
                xv = *(const bf16x8*)&y[base];
                gv = *(const bf16x8*)&y[base + HF];
            }
            *(bf16x8*)&xs[p * 64 + cseg] = xv;
            *(bf16x8*)&gs[p * 64 + cseg] = gv;
        }
    }
    float wx[9], wg[9];
    #pragma unroll
    for (int t = 0; t < 9; t++) {
        wx[t] = dw_w[(size_t)(c0 + cc) * 9 + t];
        wg[t] = dw_w[(size_t)(HF + c0 + cc) * 9 + t];
    }
    float bx = dw_b[c0 + cc], bg = dw_b[HF + c0 + cc];
    __syncthreads();
    for (int p = pg * 16; p < pg * 16 + 16; p++) {
        int py = p >> 3, px = p & 7;
        float ax = bx, ag = bg;
        #pragma unroll
        for (int dy = 0; dy < 3; dy++)
            #pragma unroll
            for (int dx = 0; dx < 3; dx++) {
                int q = (py + dy) * 10 + (px + dx);
                ax += (float)xs[q * 64 + cc] * wx[dy * 3 + dx];
                ag += (float)gs[q * 64 + cc] * wg[dy * 3 + dx];
            }
        float out = ax * (ag / (1.f + __expf(-ag)));
        g[((size_t)(b * NTOK + (ty + py) * 32 + tx + px)) * HF + c0 + cc] = (bf16)out;
    }
}

// final: out = x1 + comb(m)*g_mlp
__global__ __launch_bounds__(256) void add_mlp(const bf16* __restrict__ mm, const bf16* __restrict__ ss,
                                               float* __restrict__ xo) {
    int b = blockIdx.x / 4608;
    size_t idx = (size_t)blockIdx.x * 256 + threadIdx.x;
    size_t local = idx - (size_t)b * NPB;
    int c = (int)(local >> 12), hw = (int)(local & 4095);
    int hh = hw >> 6, w = hw & 63;
    int n = (hh >> 1) * 32 + (w >> 1);
    int dd = c * 4 + (hh & 1) * 2 + (w & 1);
    float mv = (float)mm[(size_t)dd * 4096 + b * NTOK + n];
    float g = (float)ss[(size_t)(1440 + c) * 16384 + b * HW + hw];
    xo[idx] = xo[idx] + mv * g;
}

// ---------------------------------------------------------------------------
extern "C" void kernel_launch(void* const* d_in, const int* in_sizes, int n_in,
                              void* d_out, int out_size, void* d_ws, size_t ws_size,
                              hipStream_t stream) {
    (void)in_sizes; (void)n_in; (void)out_size; (void)ws_size;
    const float* x      = (const float*)d_in[0];
    const float* cond   = (const float*)d_in[1];
    const float* gtok   = (const float*)d_in[2];
    const float* ttok   = (const float*)d_in[3];
    const float* ss_w   = (const float*)d_in[4];
    const float* ss_b   = (const float*)d_in[5];
    const float* qkv_w  = (const float*)d_in[6];
    const float* proj_w = (const float*)d_in[7];
    const float* proj_b = (const float*)d_in[8];
    const float* inv_w  = (const float*)d_in[9];
    const float* inv_b  = (const float*)d_in[10];
    const float* dw_w   = (const float*)d_in[11];
    const float* dw_b   = (const float*)d_in[12];
    const float* pw_w   = (const float*)d_in[13];
    float* out = (float*)d_out;
    char* ws = (char*)d_ws;

    float* sums  = (float*)(ws + OFF_SUMS);
    float* PART1 = (float*)(ws + OFF_PART1);
    float* PART2 = (float*)(ws + OFF_PART2);
    bf16* SS    = (bf16*)(ws + OFF_SS);
    bf16* A1    = (bf16*)(ws + OFF_A1);
    bf16* T     = (bf16*)(ws + OFF_T);
    bf16* QKV   = (bf16*)(ws + OFF_QKV);
    float* VK   = (float*)(ws + OFF_VK);
    bf16* ATT   = (bf16*)(ws + OFF_ATT);
    bf16* APROJ = (bf16*)(ws + OFF_APROJ);
    bf16* T2    = (bf16*)(ws + OFF_T2);
    bf16* Y     = (bf16*)(ws + OFF_Y);
    bf16* G     = (bf16*)(ws + OFF_G);
    bf16* MM    = (bf16*)(ws + OFF_M);
    bf16* WSS   = (bf16*)(ws + OFF_WSS);
    bf16* WQKV  = (bf16*)(ws + OFF_WQKV);
    bf16* WPROJ = (bf16*)(ws + OFF_WPROJ);
    bf16* WINV  = (bf16*)(ws + OFF_WINV);
    bf16* WPW   = (bf16*)(ws + OFF_WPW);

    cvt_bf16<<<2916, 256, 0, stream>>>(ss_w, WSS, C6 * C6 / 4);
    cvt_bf16<<<3888, 256, 0, stream>>>(qkv_w, WQKV, 3456 * DD / 4);
    cvt_bf16<<<1296, 256, 0, stream>>>(proj_w, WPROJ, DD * DD / 4);
    cvt_bf16<<<10368, 256, 0, stream>>>(inv_w, WINV, HF2 * DD / 4);
    cvt_bf16<<<5184, 256, 0, stream>>>(pw_w, WPW, DD * HF / 4);

    ln_stats<<<1152, 256, 0, stream>>>(x, PART1);
    reduce_part<<<4, 256, 0, stream>>>(PART1, sums, 288, 0);
    prep_cond<<<dim3(64, 27, 4), 256, 0, stream>>>(cond, A1);
    // ss = silu(cond) @ ss_w^T + ss_b, out [o][16384]  (256^2 8-wave kernel)
    gemm256<0, 1><<<dim3(64, 7), 512, 0, stream>>>(WSS, A1, ss_b, SS, C6, 16384, C6, 0);
    build_tok_t<<<dim3(9, 32, 4), 256, 0, stream>>>(x, SS, sums, 0, 0, 288, T, 2, SEQ);
    copy_gt<<<dim3(2, 4), 256, 0, stream>>>(gtok, ttok, T);
    // qkv, relu on first 2304 output channels
    gemm256<1, 0><<<dim3(17, 14), 512, 0, stream>>>(WQKV, T, nullptr, QKV, 3456, RTOT, DD, 2304);
    hipMemsetAsync(ws + OFF_VK, 0, (size_t)144 * 1056 * 4, stream);
    attn_vk<<<576, 256, 0, stream>>>(QKV, VK);
    attn_out<<<dim3(17, 144), 256, 0, stream>>>(QKV, VK, ATT);
    // proj (small grid -> 128^2 kernel)
    gemm_bt<0, 1><<<dim3(33, 9), 256, 0, stream>>>(WPROJ, ATT, proj_b, APROJ, DD, RTOT, DD, 0);
    add_attn<<<18432, 256, 0, stream>>>(x, APROJ, SS, out, PART2);
    reduce_part<<<4, 256, 0, stream>>>(PART2, sums, 4608, 8);
    build_tok_t<<<dim3(9, 32, 4), 256, 0, stream>>>(out, SS, sums, 8, 864, 1152, T2, 0, 1024);
    // MLP expand + silu, out [r][9216]
    gemm256<2, 2><<<dim3(36, 16), 512, 0, stream>>>(T2, WINV, inv_b, Y, 4096, HF2, DD, 0);
    dwglu<<<dim3(72, 16, 4), 256, 0, stream>>>(Y, dw_w, dw_b, G);
    // MLP project, out [o][4096] (small grid -> 128^2 kernel)
    gemm_bt<0, 0><<<dim3(32, 9), 256, 0, stream>>>(WPW, G, nullptr, MM, DD, 4096, HF, 0);
    add_mlp<<<18432, 256, 0, stream>>>(MM, SS, out);
}

// Round 8
// 929.867 us; speedup vs baseline: 1.1452x; 1.0913x over previous
//
#include <hip/hip_runtime.h>
#include <hip/hip_bf16.h>
#include <cstdint>

// ---------------------------------------------------------------------------
// SANA MS-AdaLN block on MI355X.
// R1: LN stats via per-block partials. R4: LDS-DMA fill conflicts structural.
// R5a/R6: GROUP_M + XCD-chunked bijective swizzle (FETCH 401->95 MB).
// R7: 2-phase dbuf + counted vmcnt(4): VALUBusy 39->16, MfmaUtil 23->26.
// R8: 3-buf 2-deep prefetch vmcnt(8): neutral -> structure-bound (m97-class
//   ceiling for the 128²/BK=32 2-barrier loop).
// R9-R11: 256²/BK=64/8-wave phase-interleaved template attempted 3x:
//   R9 container fail; R10 8 pinned phases = 224 µs (order-pinning, m141);
//   R11 2 regions = 208 µs, MfmaUtil 16.8%. All lose to gemm_bt's 164 µs /
//   26%. Per pre-committed rule: structure abandoned; revert to gemm_bt.
// R12: consolidation. GEMMs back to R8-green gemm_bt. Kept: dwglu bf16x8
//   staging (R9). New: attn_vk de-atomicized (per-s-split partial buffers
//   VK[144][4][1056], attn_out sums 4 partials; memset dropped - every slot
//   fully written). Bench: container failed twice.
// R13: R12 resubmitted unchanged. Audit found no fault class (gemm_bt
//   byte-identical to R3-green; attn changes are plain stores, hang-free;
//   workspace extents verified). Infra telemetry (npz pushes 955-1621 s in
//   adjacent rounds, R4->R10 resubmit precedent) points to flake.
// ---------------------------------------------------------------------------

typedef __bf16 bf16;
typedef bf16 bf16x8 __attribute__((ext_vector_type(8)));
typedef bf16 bf16x4 __attribute__((ext_vector_type(4)));
typedef float f32x4 __attribute__((ext_vector_type(4)));

typedef const __attribute__((address_space(1))) void gas_void;
typedef __attribute__((address_space(3))) void las_void;

__device__ __forceinline__ void gload16(const bf16* g, bf16* l) {
    __builtin_amdgcn_global_load_lds((gas_void*)g, (las_void*)l, 16, 0, 0);
}

// ---- problem constants ----
#define BB 4
#define CC 288
#define HW 4096          // 64*64
#define C6 1728
#define DD 1152
#define SEQ 1026
#define RTOT 4104        // 4*1026
#define NTOK 1024
#define HF 4608
#define HF2 9216
#define NPB 1179648      // elements per batch sample (288*4096)

// ---- workspace layout (bytes) ----
static constexpr size_t OFF_SUMS = 0;                                   // 16 floats
static constexpr size_t OFF_SS   = 256;                                 // bf16 [1728][16384]
static constexpr size_t SS_BYTES = (size_t)C6 * 16384 * 2;              // 56,623,104
static constexpr size_t OFF_R2   = OFF_SS + SS_BYTES;
// phase A
static constexpr size_t OFF_PART1= OFF_R2;                              // f32 [1152][2]
static constexpr size_t OFF_A1   = OFF_R2;                              // bf16 [16384][1728]
// phase B
static constexpr size_t OFF_T    = OFF_R2;                              // bf16 [4104][1152]
static constexpr size_t OFF_QKV  = OFF_T   + (size_t)RTOT*DD*2;         // bf16 [3456][4104]
static constexpr size_t OFF_PART2= OFF_QKV;                             // f32 [18432][2]
static constexpr size_t OFF_VK   = OFF_QKV + (size_t)3456*RTOT*2;       // f32 [144][4][1056] partials
static constexpr size_t OFF_ATT  = OFF_VK  + (size_t)144*4*1056*4;      // bf16 [4104][1152]
static constexpr size_t OFF_APROJ= OFF_ATT + (size_t)RTOT*DD*2;         // bf16 [1152][4104]
// phase C
static constexpr size_t OFF_T2   = OFF_R2;                              // bf16 [4096][1152]
static constexpr size_t OFF_Y    = OFF_T2  + (size_t)4096*DD*2;         // bf16 [4096][9216]
static constexpr size_t OFF_G    = OFF_Y   + (size_t)4096*HF2*2;        // bf16 [4096][4608]
static constexpr size_t OFF_M    = OFF_G   + (size_t)4096*HF*2;         // bf16 [1152][4096]
// converted weights (persistent)
static constexpr size_t OFF_W    = OFF_R2  + 132120576;
static constexpr size_t OFF_WSS  = OFF_W;
static constexpr size_t OFF_WQKV = OFF_WSS  + (size_t)C6*C6*2;
static constexpr size_t OFF_WPROJ= OFF_WQKV + (size_t)3456*DD*2;
static constexpr size_t OFF_WINV = OFF_WPROJ+ (size_t)DD*DD*2;
static constexpr size_t OFF_WPW  = OFF_WINV + (size_t)HF2*DD*2;

// ---------------------------------------------------------------------------
// fp32 -> bf16 weight conversion
__global__ __launch_bounds__(256) void cvt_bf16(const float* __restrict__ s,
                                                bf16* __restrict__ d, int n4) {
    int i = blockIdx.x * 256 + threadIdx.x;
    if (i < n4) {
        float4 v = ((const float4*)s)[i];
        bf16x4 o = {(bf16)v.x, (bf16)v.y, (bf16)v.z, (bf16)v.w};
        ((bf16x4*)d)[i] = o;
    }
}

// ---------------------------------------------------------------------------
__device__ __forceinline__ void block_reduce2_store(float s1, float s2, float* dst) {
    #pragma unroll
    for (int o = 32; o > 0; o >>= 1) { s1 += __shfl_down(s1, o); s2 += __shfl_down(s2, o); }
    __shared__ float r1[4], r2[4];
    int wave = threadIdx.x >> 6, lane = threadIdx.x & 63;
    if (lane == 0) { r1[wave] = s1; r2[wave] = s2; }
    __syncthreads();
    if (threadIdx.x == 0) {
        dst[0] = r1[0] + r1[1] + r1[2] + r1[3];
        dst[1] = r2[0] + r2[1] + r2[2] + r2[3];
    }
}

__global__ __launch_bounds__(256) void ln_stats(const float* __restrict__ x, float* __restrict__ part) {
    const float* base = x + (size_t)blockIdx.x * 4096;
    float s1 = 0.f, s2 = 0.f;
    #pragma unroll
    for (int it = 0; it < 4; it++) {
        float4 v = ((const float4*)base)[it * 256 + threadIdx.x];
        s1 += v.x + v.y + v.z + v.w;
        s2 += v.x * v.x + v.y * v.y + v.z * v.z + v.w * v.w;
    }
    block_reduce2_store(s1, s2, part + (size_t)blockIdx.x * 2);
}

__global__ __launch_bounds__(256) void reduce_part(const float* __restrict__ part, float* __restrict__ sums,
                                                   int nper, int out_off) {
    int b = blockIdx.x;
    float s1 = 0.f, s2 = 0.f;
    for (int i = threadIdx.x; i < nper; i += 256) {
        s1 += part[(size_t)(b * nper + i) * 2];
        s2 += part[(size_t)(b * nper + i) * 2 + 1];
    }
    block_reduce2_store(s1, s2, sums + out_off + b * 2);
}

// ---------------------------------------------------------------------------
// silu(cond) transpose: (b, k, hw) f32 -> A1[(b,hw)][k] bf16. grid (64,27,4)
__global__ __launch_bounds__(256) void prep_cond(const float* __restrict__ cond, bf16* __restrict__ A1) {
    __shared__ float tile[64][65];
    int b = blockIdx.z, k0 = blockIdx.y * 64, h0 = blockIdx.x * 64;
    int col = threadIdx.x & 63, r4 = threadIdx.x >> 6;
    const float* src = cond + ((size_t)b * C6 + k0) * HW + h0;
    #pragma unroll
    for (int p = 0; p < 16; p++) {
        int kk = r4 + p * 4;
        float v = src[(size_t)kk * HW + col];
        tile[col][kk] = v / (1.f + __expf(-v));
    }
    __syncthreads();
    bf16* dst = A1 + ((size_t)(b * HW + h0)) * C6 + k0;
    #pragma unroll
    for (int p = 0; p < 16; p++) {
        int rr = r4 + p * 4;
        dst[(size_t)rr * C6 + col] = (bf16)tile[rr][col];
    }
}

// ---------------------------------------------------------------------------
// gemm_bt: C[m][n] = sum_k A[m][k]*B[n][k]  (both operands k-contiguous bf16)
// EP: 0=none, 1=relu if m<reluLimit, 2=silu.  BIAS: 0=none, 1=per-m, 2=per-n.
// Swizzle = XCD-chunk (bijective) composed with GROUP_M=8 (R6).
// K-loop = 3-phase triple-buffer, 2-deep prefetch, counted vmcnt(8) (R8).
template <int EP, int BIAS>
__global__ __launch_bounds__(256) void gemm_bt(const bf16* __restrict__ A, const bf16* __restrict__ B,
                                               const float* __restrict__ bias, bf16* __restrict__ C,
                                               int M, int N, int K, int reluLimit) {
    __shared__ __align__(16) bf16 As[3][128 * 32];
    __shared__ __align__(16) bf16 Bs[3][128 * 32];
    const int tid = threadIdx.x, wave = tid >> 6, lane = tid & 63;

    const int nx = gridDim.x, ny = gridDim.y, G = 8;
    int idx = blockIdx.y * nx + blockIdx.x;
    int total = nx * ny;
    int q = total >> 3, rm = total & 7;
    int xcd = idx & 7, slot = idx >> 3;
    int vid = (xcd < rm ? xcd * (q + 1) : rm * (q + 1) + (xcd - rm) * q) + slot;
    int band = vid / (G * nx);
    int r = vid - band * (G * nx);
    int gm = min(G, ny - band * G);
    const int m0 = (band * G + r % gm) * 128;
    const int n0 = (r / gm) * 128;

    const int c0 = wave * 128 + lane;
    const int c1 = c0 + 64;
    const int sw = ((c0 >> 2) & 3) ^ ((c0 >> 4) & 3);
    const int ka = (((c0 & 3) ^ sw)) * 8;
    int ra0 = min(m0 + (c0 >> 2), M - 1), ra1 = min(m0 + (c1 >> 2), M - 1);
    int rb0 = min(n0 + (c0 >> 2), N - 1), rb1 = min(n0 + (c1 >> 2), N - 1);
    const bf16* gA0 = A + (size_t)ra0 * K + ka;
    const bf16* gA1 = A + (size_t)ra1 * K + ka;
    const bf16* gB0 = B + (size_t)rb0 * K + ka;
    const bf16* gB1 = B + (size_t)rb1 * K + ka;

    const int wm = (wave >> 1) * 64, wn = (wave & 1) * 64;
    const int l15 = lane & 15;
    const int sr = (l15 & 3) ^ ((l15 >> 2) & 3);
    const int fc = ((lane >> 4) ^ sr) * 8;
    const int fao = (wm + l15) * 32 + fc;
    const int fbo = (wn + l15) * 32 + fc;
    const int lwo = wave * 1024;

    f32x4 acc[4][4];
    #pragma unroll
    for (int i = 0; i < 4; i++)
        #pragma unroll
        for (int j = 0; j < 4; j++) acc[i][j] = (f32x4){0.f, 0.f, 0.f, 0.f};

    auto STAGE = [&](int buf) {
        gload16(gA0, &As[buf][lwo]);
        gload16(gA1, &As[buf][lwo + 512]);
        gload16(gB0, &Bs[buf][lwo]);
        gload16(gB1, &Bs[buf][lwo + 512]);
        gA0 += 32; gA1 += 32; gB0 += 32; gB1 += 32;
    };
    auto COMP = [&](int buf) {
        const bf16* fa = &As[buf][fao];
        const bf16* fb = &Bs[buf][fbo];
        bf16x8 af[4], bvv[4];
        #pragma unroll
        for (int i = 0; i < 4; i++) af[i] = *(const bf16x8*)(fa + i * 16 * 32);
        #pragma unroll
        for (int j = 0; j < 4; j++) bvv[j] = *(const bf16x8*)(fb + j * 16 * 32);
        #pragma unroll
        for (int i = 0; i < 4; i++)
            #pragma unroll
            for (int j = 0; j < 4; j++)
                acc[i][j] = __builtin_amdgcn_mfma_f32_16x16x32_bf16(af[i], bvv[j], acc[i][j], 0, 0, 0);
    };
    auto STEP = [&](int cbuf, int sbuf) {
        STAGE(sbuf);
        asm volatile("s_waitcnt vmcnt(8)" ::: "memory");
        __builtin_amdgcn_s_barrier();
        asm volatile("" ::: "memory");
        COMP(cbuf);
        asm volatile("" ::: "memory");
        __builtin_amdgcn_s_barrier();
    };

    const int nt = K >> 5;                 // all call sites % 3 == 0 (54/36/144)
    STAGE(0);
    STAGE(1);
    for (int it = 0; it < nt / 3 - 1; ++it) {
        STEP(0, 2);
        STEP(1, 0);
        STEP(2, 1);
    }
    STEP(0, 2);
    asm volatile("s_waitcnt vmcnt(4)" ::: "memory");
    __builtin_amdgcn_s_barrier();
    asm volatile("" ::: "memory");
    COMP(1);
    asm volatile("" ::: "memory");
    asm volatile("s_waitcnt vmcnt(0)" ::: "memory");
    __builtin_amdgcn_s_barrier();
    asm volatile("" ::: "memory");
    COMP(2);

    const int mq = (lane >> 4) * 4, nl = lane & 15;
    #pragma unroll
    for (int i = 0; i < 4; i++) {
        #pragma unroll
        for (int j = 0; j < 4; j++) {
            int n = n0 + wn + j * 16 + nl;
            if (n < N) {
                #pragma unroll
                for (int r2 = 0; r2 < 4; r2++) {
                    int m = m0 + wm + i * 16 + mq + r2;
                    if (m < M) {
                        float v = acc[i][j][r2];
                        if (BIAS == 1) v += bias[m];
                        else if (BIAS == 2) v += bias[n];
                        if (EP == 1) { if (m < reluLimit) v = fmaxf(v, 0.f); }
                        else if (EP == 2) { v = v / (1.f + __expf(-v)); }
                        C[(size_t)m * N + n] = (bf16)v;
                    }
                }
            }
        }
    }
}

// ---------------------------------------------------------------------------
// token build (coalesced): grid (9 cchunk, 32 n1, 4 b), block 256.
__global__ __launch_bounds__(256) void build_tok_t(const float* __restrict__ xs, const bf16* __restrict__ ss,
                                                   const float* __restrict__ sums, int soff, int shb, int scb,
                                                   bf16* __restrict__ dst, int tokoff, int seqstride) {
    __shared__ bf16 tl[32][132];
    int cch = blockIdx.x, n1 = blockIdx.y, b = blockIdx.z;
    int c0 = cch * 32;
    int tid = threadIdx.x, cl = tid >> 3, wseg = tid & 7;

    float mu = sums[soff + b * 2] * (1.f / (float)NPB);
    float var = sums[soff + b * 2 + 1] * (1.f / (float)NPB) - mu * mu;
    float rsig = rsqrtf(var + 1e-6f);

    int c = c0 + cl;
    #pragma unroll
    for (int hh = 0; hh < 2; hh++) {
        int hw = (2 * n1 + hh) * 64 + wseg * 8;
        const float* xp = xs + ((size_t)b * CC + c) * HW + hw;
        float4 x0 = ((const float4*)xp)[0];
        float4 x1 = ((const float4*)xp)[1];
        bf16x8 scv = *(const bf16x8*)(ss + (size_t)(scb + c) * 16384 + b * HW + hw);
        bf16x8 shv = *(const bf16x8*)(ss + (size_t)(shb + c) * 16384 + b * HW + hw);
        float xv[8] = {x0.x, x0.y, x0.z, x0.w, x1.x, x1.y, x1.z, x1.w};
        #pragma unroll
        for (int k = 0; k < 8; k++) {
            int w = wseg * 8 + k;
            float v = (xv[k] - mu) * rsig * (1.f + (float)scv[k]) + (float)shv[k];
            tl[w >> 1][cl * 4 + hh * 2 + (w & 1)] = (bf16)v;
        }
    }
    __syncthreads();
    int token = tid >> 3, seg = (tid & 7) * 16;
    bf16* drow = dst + ((size_t)(b * seqstride + tokoff + n1 * 32 + token)) * DD + c0 * 4 + seg;
    *(bf16x8*)drow = *(const bf16x8*)&tl[token][seg];
    *(bf16x8*)(drow + 8) = *(const bf16x8*)&tl[token][seg + 8];
}

__global__ __launch_bounds__(256) void copy_gt(const float* __restrict__ gtok, const float* __restrict__ ttok,
                                               bf16* __restrict__ T) {
    int which = blockIdx.x, b = blockIdx.y;
    const float* src = (which == 0 ? gtok : ttok) + b * DD;
    bf16* dst = T + (size_t)(b * SEQ + which) * DD;
    for (int d = threadIdx.x; d < DD; d += 256) dst[d] = (bf16)src[d];
}

// ---------------------------------------------------------------------------
// attention: vk_part[bh][sb][e*32+d] = sum_{s in split sb} vpad[s,e]*k[s,d]
// grid 144*4 (s-split); plain stores to per-split partials (R12: no atomics).
__global__ __launch_bounds__(256) void attn_vk(const bf16* __restrict__ qkv, float* __restrict__ vk) {
    int bh = blockIdx.x >> 2, sb = blockIdx.x & 3;
    int b = bh / 36, h = bh % 36;
    int s_begin = sb * 288;
    int s_end = min(s_begin + 288, SEQ);
    const bf16* kbase = qkv + (size_t)(DD + h * 32) * RTOT + b * SEQ;
    const bf16* vbase = qkv + (size_t)(2 * DD + h * 32) * RTOT + b * SEQ;
    __shared__ __align__(16) bf16 kk[32][80];
    __shared__ __align__(16) bf16 vv[32][80];
    int tid = threadIdx.x;
    int e = tid >> 3, dg = (tid & 7) * 4;
    int lrow = tid >> 3, lcol = (tid & 7) * 8;
    float a0 = 0.f, a1 = 0.f, a2 = 0.f, a3 = 0.f, aD = 0.f;
    for (int s0 = s_begin; s0 < s_end; s0 += 64) {
        __syncthreads();
        #pragma unroll
        for (int j = 0; j < 8; j++) {
            int s = s0 + lcol + j;
            bool ok = s < s_end;
            kk[lrow][lcol + j] = ok ? kbase[(size_t)lrow * RTOT + s] : (bf16)0.f;
            vv[lrow][lcol + j] = ok ? vbase[(size_t)lrow * RTOT + s] : (bf16)0.f;
        }
        __syncthreads();
        #pragma unroll
        for (int j0 = 0; j0 < 64; j0 += 8) {
            bf16x8 vvv = *(const bf16x8*)&vv[e][j0];
            bf16x8 k0 = *(const bf16x8*)&kk[dg + 0][j0];
            bf16x8 k1 = *(const bf16x8*)&kk[dg + 1][j0];
            bf16x8 k2 = *(const bf16x8*)&kk[dg + 2][j0];
            bf16x8 k3 = *(const bf16x8*)&kk[dg + 3][j0];
            #pragma unroll
            for (int j = 0; j < 8; j++) {
                float vf = (float)vvv[j];
                a0 += vf * (float)k0[j];
                a1 += vf * (float)k1[j];
                a2 += vf * (float)k2[j];
                a3 += vf * (float)k3[j];
            }
            if (tid < 32) {
                bf16x8 kd = *(const bf16x8*)&kk[tid][j0];
                #pragma unroll
                for (int j = 0; j < 8; j++) aD += (float)kd[j];
            }
        }
    }
    float* dst = vk + ((size_t)bh * 4 + sb) * 1056;
    dst[e * 32 + dg + 0] = a0;
    dst[e * 32 + dg + 1] = a1;
    dst[e * 32 + dg + 2] = a2;
    dst[e * 32 + dg + 3] = a3;
    if (tid < 32) dst[1024 + tid] = aD;
}

// attention normalize: out[s][e] = (sum_d vk[e][d] q[s][d]) / (den + eps)
// vks = sum over the 4 s-split partials (R12).
__global__ __launch_bounds__(256) void attn_out(const bf16* __restrict__ qkv, const float* __restrict__ vk,
                                                bf16* __restrict__ att) {
    int bh = blockIdx.y, b = bh / 36, h = bh % 36;
    int s0 = blockIdx.x * 64;
    __shared__ float vks[1056];
    __shared__ __align__(16) bf16 qs[32][80];
    int tid = threadIdx.x;
    const float* vp = vk + (size_t)bh * 4 * 1056;
    for (int i = tid; i < 1056; i += 256)
        vks[i] = vp[i] + vp[1056 + i] + vp[2112 + i] + vp[3168 + i];
    const bf16* qbase = qkv + (size_t)(h * 32) * RTOT + b * SEQ;
    int lrow = tid >> 3, lcol = (tid & 7) * 8;
    #pragma unroll
    for (int j = 0; j < 8; j++) {
        int s = s0 + lcol + j;
        qs[lrow][lcol + j] = (s < SEQ) ? qbase[(size_t)lrow * RTOT + s] : (bf16)0.f;
    }
    __syncthreads();
    int sl = tid >> 2, eg = (tid & 3) * 8;
    int s = s0 + sl;
    float num[8] = {0.f, 0.f, 0.f, 0.f, 0.f, 0.f, 0.f, 0.f};
    float den = 0.f;
    #pragma unroll
    for (int d = 0; d < 32; d++) {
        float qv = (float)qs[d][sl];
        den += vks[1024 + d] * qv;
        #pragma unroll
        for (int t = 0; t < 8; t++) num[t] += vks[(eg + t) * 32 + d] * qv;
    }
    if (s < SEQ) {
        float inv = 1.f / (den + 1e-8f);
        bf16* dst = att + ((size_t)(b * SEQ + s)) * DD + h * 32 + eg;
        #pragma unroll
        for (int t = 0; t < 8; t++) dst[t] = (bf16)(num[t] * inv);
    }
}

// ---------------------------------------------------------------------------
__global__ __launch_bounds__(256) void add_attn(const float* __restrict__ x, const bf16* __restrict__ aproj,
                                                const bf16* __restrict__ ss, float* __restrict__ xo,
                                                float* __restrict__ part) {
    int b = blockIdx.x / 4608;
    size_t idx = (size_t)blockIdx.x * 256 + threadIdx.x;
    size_t local = idx - (size_t)b * NPB;
    int c = (int)(local >> 12), hw = (int)(local & 4095);
    int hh = hw >> 6, w = hw & 63;
    int n = (hh >> 1) * 32 + (w >> 1);
    int dd = c * 4 + (hh & 1) * 2 + (w & 1);
    float a = (float)aproj[(size_t)dd * RTOT + b * SEQ + 2 + n];
    float g = (float)ss[(size_t)(576 + c) * 16384 + b * HW + hw];
    float v = x[idx] + a * g;
    xo[idx] = v;
    block_reduce2_store(v, v * v, part + (size_t)blockIdx.x * 2);
}

// ---------------------------------------------------------------------------
// depthwise 3x3 + bias + GLU. grid (72 cchunk, 16 tile, 4 b), block 256.
// R9: staging vectorized bf16x8 (was scalar bf16 loads).
__global__ __launch_bounds__(256) void dwglu(const bf16* __restrict__ y, const float* __restrict__ dw_w,
                                             const float* __restrict__ dw_b, bf16* __restrict__ g) {
    __shared__ __align__(16) bf16 xs[6400];
    __shared__ __align__(16) bf16 gs[6400];
    int b = blockIdx.z, tile = blockIdx.y, c0 = blockIdx.x * 64;
    int ty = (tile >> 2) * 8, tx = (tile & 3) * 8;
    int tid = threadIdx.x, cc = tid & 63, pg = tid >> 6;
    int pos8 = tid >> 3, cseg = (tid & 7) * 8;
    bf16x8 z = {(bf16)0.f, (bf16)0.f, (bf16)0.f, (bf16)0.f,
                (bf16)0.f, (bf16)0.f, (bf16)0.f, (bf16)0.f};
    #pragma unroll
    for (int p0 = 0; p0 < 128; p0 += 32) {
        int p = p0 + pos8;
        if (p < 100) {
            int py = ty + p / 10 - 1, px = tx + p % 10 - 1;
            bool in = (py >= 0 && py < 32 && px >= 0 && px < 32);
            bf16x8 xv = z, gv = z;
            if (in) {
                size_t base = ((size_t)(b * NTOK + py * 32 + px)) * HF2 + c0 + cseg;
                xv = *(const bf16x8*)&y[base];
                gv = *(const bf16x8*)&y[base + HF];
            }
            *(bf16x8*)&xs[p * 64 + cseg] = xv;
            *(bf16x8*)&gs[p * 64 + cseg] = gv;
        }
    }
    float wx[9], wg[9];
    #pragma unroll
    for (int t = 0; t < 9; t++) {
        wx[t] = dw_w[(size_t)(c0 + cc) * 9 + t];
        wg[t] = dw_w[(size_t)(HF + c0 + cc) * 9 + t];
    }
    float bx = dw_b[c0 + cc], bg = dw_b[HF + c0 + cc];
    __syncthreads();
    for (int p = pg * 16; p < pg * 16 + 16; p++) {
        int py = p >> 3, px = p & 7;
        float ax = bx, ag = bg;
        #pragma unroll
        for (int dy = 0; dy < 3; dy++)
            #pragma unroll
            for (int dx = 0; dx < 3; dx++) {
                int q = (py + dy) * 10 + (px + dx);
                ax += (float)xs[q * 64 + cc] * wx[dy * 3 + dx];
                ag += (float)gs[q * 64 + cc] * wg[dy * 3 + dx];
            }
        float out = ax * (ag / (1.f + __expf(-ag)));
        g[((size_t)(b * NTOK + (ty + py) * 32 + tx + px)) * HF + c0 + cc] = (bf16)out;
    }
}

// final: out = x1 + comb(m)*g_mlp
__global__ __launch_bounds__(256) void add_mlp(const bf16* __restrict__ mm, const bf16* __restrict__ ss,
                                               float* __restrict__ xo) {
    int b = blockIdx.x / 4608;
    size_t idx = (size_t)blockIdx.x * 256 + threadIdx.x;
    size_t local = idx - (size_t)b * NPB;
    int c = (int)(local >> 12), hw = (int)(local & 4095);
    int hh = hw >> 6, w = hw & 63;
    int n = (hh >> 1) * 32 + (w >> 1);
    int dd = c * 4 + (hh & 1) * 2 + (w & 1);
    float mv = (float)mm[(size_t)dd * 4096 + b * NTOK + n];
    float g = (float)ss[(size_t)(1440 + c) * 16384 + b * HW + hw];
    xo[idx] = xo[idx] + mv * g;
}

// ---------------------------------------------------------------------------
extern "C" void kernel_launch(void* const* d_in, const int* in_sizes, int n_in,
                              void* d_out, int out_size, void* d_ws, size_t ws_size,
                              hipStream_t stream) {
    (void)in_sizes; (void)n_in; (void)out_size; (void)ws_size;
    const float* x      = (const float*)d_in[0];
    const float* cond   = (const float*)d_in[1];
    const float* gtok   = (const float*)d_in[2];
    const float* ttok   = (const float*)d_in[3];
    const float* ss_w   = (const float*)d_in[4];
    const float* ss_b   = (const float*)d_in[5];
    const float* qkv_w  = (const float*)d_in[6];
    const float* proj_w = (const float*)d_in[7];
    const float* proj_b = (const float*)d_in[8];
    const float* inv_w  = (const float*)d_in[9];
    const float* inv_b  = (const float*)d_in[10];
    const float* dw_w   = (const float*)d_in[11];
    const float* dw_b   = (const float*)d_in[12];
    const float* pw_w   = (const float*)d_in[13];
    float* out = (float*)d_out;
    char* ws = (char*)d_ws;

    float* sums  = (float*)(ws + OFF_SUMS);
    float* PART1 = (float*)(ws + OFF_PART1);
    float* PART2 = (float*)(ws + OFF_PART2);
    bf16* SS    = (bf16*)(ws + OFF_SS);
    bf16* A1    = (bf16*)(ws + OFF_A1);
    bf16* T     = (bf16*)(ws + OFF_T);
    bf16* QKV   = (bf16*)(ws + OFF_QKV);
    float* VK   = (float*)(ws + OFF_VK);
    bf16* ATT   = (bf16*)(ws + OFF_ATT);
    bf16* APROJ = (bf16*)(ws + OFF_APROJ);
    bf16* T2    = (bf16*)(ws + OFF_T2);
    bf16* Y     = (bf16*)(ws + OFF_Y);
    bf16* G     = (bf16*)(ws + OFF_G);
    bf16* MM    = (bf16*)(ws + OFF_M);
    bf16* WSS   = (bf16*)(ws + OFF_WSS);
    bf16* WQKV  = (bf16*)(ws + OFF_WQKV);
    bf16* WPROJ = (bf16*)(ws + OFF_WPROJ);
    bf16* WINV  = (bf16*)(ws + OFF_WINV);
    bf16* WPW   = (bf16*)(ws + OFF_WPW);

    cvt_bf16<<<2916, 256, 0, stream>>>(ss_w, WSS, C6 * C6 / 4);
    cvt_bf16<<<3888, 256, 0, stream>>>(qkv_w, WQKV, 3456 * DD / 4);
    cvt_bf16<<<1296, 256, 0, stream>>>(proj_w, WPROJ, DD * DD / 4);
    cvt_bf16<<<10368, 256, 0, stream>>>(inv_w, WINV, HF2 * DD / 4);
    cvt_bf16<<<5184, 256, 0, stream>>>(pw_w, WPW, DD * HF / 4);

    ln_stats<<<1152, 256, 0, stream>>>(x, PART1);
    reduce_part<<<4, 256, 0, stream>>>(PART1, sums, 288, 0);
    prep_cond<<<dim3(64, 27, 4), 256, 0, stream>>>(cond, A1);
    // ss = silu(cond) @ ss_w^T + ss_b, out [o][16384]
    gemm_bt<0, 1><<<dim3(128, 14), 256, 0, stream>>>(WSS, A1, ss_b, SS, C6, 16384, C6, 0);
    build_tok_t<<<dim3(9, 32, 4), 256, 0, stream>>>(x, SS, sums, 0, 0, 288, T, 2, SEQ);
    copy_gt<<<dim3(2, 4), 256, 0, stream>>>(gtok, ttok, T);
    // qkv, relu on first 2304 output channels
    gemm_bt<1, 0><<<dim3(33, 27), 256, 0, stream>>>(WQKV, T, nullptr, QKV, 3456, RTOT, DD, 2304);
    attn_vk<<<576, 256, 0, stream>>>(QKV, VK);
    attn_out<<<dim3(17, 144), 256, 0, stream>>>(QKV, VK, ATT);
    // proj
    gemm_bt<0, 1><<<dim3(33, 9), 256, 0, stream>>>(WPROJ, ATT, proj_b, APROJ, DD, RTOT, DD, 0);
    add_attn<<<18432, 256, 0, stream>>>(x, APROJ, SS, out, PART2);
    reduce_part<<<4, 256, 0, stream>>>(PART2, sums, 4608, 8);
    build_tok_t<<<dim3(9, 32, 4), 256, 0, stream>>>(out, SS, sums, 8, 864, 1152, T2, 0, 1024);
    // MLP expand + silu, out [r][9216]
    gemm_bt<2, 2><<<dim3(72, 32), 256, 0, stream>>>(T2, WINV, inv_b, Y, 4096, HF2, DD, 0);
    dwglu<<<dim3(72, 16, 4), 256, 0, stream>>>(Y, dw_w, dw_b, G);
    // MLP project, out [o][4096]
    gemm_bt<0, 0><<<dim3(32, 9), 256, 0, stream>>>(WPW, G, nullptr, MM, DD, 4096, HF, 0);
    add_mlp<<<18432, 256, 0, stream>>>(MM, SS, out);
}